// Round 3
// baseline (489.145 us; speedup 1.0000x reference)
//
#include <hip/hip_runtime.h>
#include <string.h>

#define Dims 256
#define BM 32
#define BN 32
#define KC 128
#define NSEG 8

typedef short bf16x8 __attribute__((ext_vector_type(8)));
typedef float f32x4 __attribute__((ext_vector_type(4)));

typedef __attribute__((address_space(3))) void lds_void;
typedef __attribute__((address_space(1))) const void gbl_void;

__device__ __forceinline__ void ldsload16(const void* g, void* l) {
  __builtin_amdgcn_global_load_lds((gbl_void*)g, (lds_void*)l, 16, 0, 0);
}

// ---------- Threefry2x32 (JAX), usable host+device ----------
__host__ __device__ inline void tf2x32(unsigned k0, unsigned k1,
                                       unsigned x0, unsigned x1,
                                       unsigned* o0, unsigned* o1) {
  unsigned ks[3] = {k0, k1, k0 ^ k1 ^ 0x1BD11BDAu};
  x0 += ks[0]; x1 += ks[1];
  const unsigned rA[4] = {13u, 15u, 26u, 6u};
  const unsigned rB[4] = {17u, 29u, 16u, 24u};
#pragma unroll
  for (int g = 0; g < 5; ++g) {
    const unsigned* rr = (g & 1) ? rB : rA;
#pragma unroll
    for (int j = 0; j < 4; ++j) {
      x0 += x1;
      x1 = (x1 << rr[j]) | (x1 >> (32u - rr[j]));
      x1 ^= x0;
    }
    x0 += ks[(g + 1) % 3];
    x1 += ks[(g + 2) % 3] + (unsigned)(g + 1);
  }
  *o0 = x0; *o1 = x1;
}

__device__ inline unsigned short f2bf(float f) {
  unsigned u = __builtin_bit_cast(unsigned, f);
  unsigned r = (u + 0x7fffu + ((u >> 16) & 1u)) >> 16;
  return (unsigned short)r;
}

// ---------- 1) stable compaction ----------
__global__ __launch_bounds__(1024) void k_compact(
    const int* __restrict__ idx_train, const int* __restrict__ y, int NT,
    int* __restrict__ chosen, int* __restrict__ benign) {
  __shared__ int wsum1[16], wsum0[16], woff1[16], woff0[16];
  int t = threadIdx.x;
  int lane = t & 63, w = t >> 6;
  int ept = (NT + 1023) >> 10;
  int base = t * ept;
  int n1 = 0, n0 = 0;
  for (int k = 0; k < ept; ++k) {
    int e = base + k;
    if (e < NT) {
      int idx = idx_train[e];
      if (y[idx] == 1) n1++; else n0++;
    }
  }
  int s1 = n1, s0 = n0;
#pragma unroll
  for (int d = 1; d < 64; d <<= 1) {
    int v1 = __shfl_up(s1, d, 64);
    int v0 = __shfl_up(s0, d, 64);
    if (lane >= d) { s1 += v1; s0 += v0; }
  }
  if (lane == 63) { wsum1[w] = s1; wsum0[w] = s0; }
  __syncthreads();
  if (t == 0) {
    int a = 0, b = 0;
    for (int i = 0; i < 16; ++i) {
      woff1[i] = a; a += wsum1[i];
      woff0[i] = b; b += wsum0[i];
    }
  }
  __syncthreads();
  int p1 = woff1[w] + s1 - n1;
  int p0 = woff0[w] + s0 - n0;
  for (int k = 0; k < ept; ++k) {
    int e = base + k;
    if (e < NT) {
      int idx = idx_train[e];
      if (y[idx] == 1) chosen[p1++] = idx; else benign[p0++] = idx;
    }
  }
}

// ---------- 2) fused sample + gather + bf16 convert + norms + argmin-init ----------
__global__ __launch_bounds__(64) void k_prep(
    const float* __restrict__ x, const int* __restrict__ chosen,
    const int* __restrict__ benign, int n, int ncap,
    unsigned span, unsigned k1a, unsigned k1b, unsigned k2a, unsigned k2b,
    unsigned mult, unsigned short* __restrict__ Cb, unsigned short* __restrict__ Bb,
    int* __restrict__ brow, float* __restrict__ normc, float* __restrict__ normb,
    unsigned long long* __restrict__ packed) {
  int b = blockIdx.x;
  int lane = threadIdx.x;
  bool isC = (b < ncap);
  int j = isC ? b : (b - ncap);
  if (isC && lane == 0) packed[j] = ~0ULL;
  unsigned short* dst = (isC ? Cb : Bb) + ((size_t)j << 8) + lane * 4;
  if (j >= n) {
    *(ushort4*)dst = (ushort4){0, 0, 0, 0};
    if (lane == 0) { if (isC) normc[j] = 0.f; else normb[j] = 3.4e38f; }
    return;
  }
  int row;
  if (isC) {
    row = chosen[j];
  } else {
    unsigned a0, a1, b0, b1;
    tf2x32(k1a, k1b, 0u, (unsigned)j, &a0, &a1);
    tf2x32(k2a, k2b, 0u, (unsigned)j, &b0, &b1);
    unsigned hi = a0 ^ a1, lo = b0 ^ b1;
    unsigned r = ((hi % span) * mult + (lo % span)) % span;
    row = benign[r];
    if (lane == 0) brow[j] = row;
  }
  float4 v = ((const float4*)(x + ((size_t)row << 8)))[lane];
  ushort4 o;
  o.x = f2bf(v.x); o.y = f2bf(v.y); o.z = f2bf(v.z); o.w = f2bf(v.w);
  *(ushort4*)dst = o;
  float s = v.x * v.x + v.y * v.y + v.z * v.z + v.w * v.w;
#pragma unroll
  for (int m = 32; m >= 1; m >>= 1) s += __shfl_xor(s, m, 64);
  if (lane == 0) { if (isC) normc[j] = s; else normb[j] = s; }
}

// ---------- 3) MFMA distance + fused argmin, A-in-regs, dbuf B via global_load_lds ----------
__global__ __launch_bounds__(256, 2) void k_mdist(
    const unsigned short* __restrict__ Cb, const unsigned short* __restrict__ Bb,
    const float* __restrict__ normc, const float* __restrict__ normb,
    int n, int ncap, unsigned long long* __restrict__ packed) {
  __shared__ __align__(16) char Bs[32768];  // 2 x 16KB double buffer
  const int tid = threadIdx.x;
  const int l = tid & 63;
  const int w = tid >> 6;
  const int lr = l & 15, lg = l >> 4;
  const int R0 = blockIdx.x * 128;
  const int ntiles = ncap >> 7;
  const int per = (ntiles + NSEG - 1) / NSEG;
  int t0 = blockIdx.y * per;
  int t1 = t0 + per; if (t1 > ntiles) t1 = ntiles;
  if (t0 >= t1) return;

  // per-wave B-staging geometry: 4 x global_load_lds(16B) per phase,
  // linear LDS dest, XOR-swizzle folded into the global source address
  const int cbase = w * 32 + (l >> 3);
  const int ssw = l & 7;
  char* const dstb = Bs + w * 4096;

  auto issue = [&](int buf, int ct, int k0byte) {
    const char* srcb = (const char*)Bb + (size_t)(ct << 7) * 512 + k0byte;
#pragma unroll
    for (int q = 0; q < 4; ++q) {
      int c = cbase + q * 8;
      const char* src = srcb + (size_t)c * 512 + ((ssw ^ (c & 7)) << 4);
      ldsload16(src, dstb + buf * 16384 + q * 1024);
    }
  };

  // prologue: start first B tile, then pull A fragments + row norms into regs
  issue(0, t0, 0);

  bf16x8 af[2][8];
  {
    const char* Abase = (const char*)Cb + (size_t)(R0 + w * 32 + lr) * 512 + lg * 16;
#pragma unroll
    for (int mf = 0; mf < 2; ++mf)
#pragma unroll
      for (int ko = 0; ko < 8; ++ko)
        af[mf][ko] = *(const bf16x8*)(Abase + mf * 16 * 512 + ko * 64);
  }
  float ncv[2][4];
#pragma unroll
  for (int mf = 0; mf < 2; ++mf)
#pragma unroll
    for (int j = 0; j < 4; ++j)
      ncv[mf][j] = normc[R0 + w * 32 + mf * 16 + lg * 4 + j];

  f32x4 acc[2][8];
#pragma unroll
  for (int mf = 0; mf < 2; ++mf)
#pragma unroll
    for (int nf = 0; nf < 8; ++nf) acc[mf][nf] = (f32x4){0.f, 0.f, 0.f, 0.f};

  float bval[2][4];
  int bcol[2][4];
#pragma unroll
  for (int mf = 0; mf < 2; ++mf)
#pragma unroll
    for (int j = 0; j < 4; ++j) { bval[mf][j] = __builtin_inff(); bcol[mf][j] = 0; }

  const int P = (t1 - t0) * 4;
  int cur = 0;
  for (int p = 0; p < P; ++p) {
    const int ct = t0 + (p >> 2);
    const int C0 = ct << 7;
    const bool epi = ((p & 3) == 3);
    const bool last = (p == P - 1);

    float nb[8];
    if (epi) {  // preload norms BEFORE issuing next loads (keeps vmcnt FIFO clean)
#pragma unroll
      for (int nf = 0; nf < 8; ++nf) nb[nf] = normb[C0 + nf * 16 + lr];
    }
    if (!last) {
      int pn = p + 1;
      issue(cur ^ 1, t0 + (pn >> 2), (pn & 3) * 128);
      asm volatile("s_waitcnt vmcnt(4)" ::: "memory");  // current tile landed; next stays in flight
    } else {
      asm volatile("s_waitcnt vmcnt(0)" ::: "memory");
    }
    __builtin_amdgcn_s_barrier();

    const char* Bbuf = Bs + cur * 16384;
#pragma unroll
    for (int ks = 0; ks < 2; ++ks) {
      bf16x8 bg[8];
#pragma unroll
      for (int nf = 0; nf < 8; ++nf) {
        int c = nf * 16 + lr;
        int slot = ks * 4 + lg;
        bg[nf] = *(const bf16x8*)(Bbuf + c * 128 + ((slot ^ (c & 7)) << 4));
      }
      const int ko = (p & 3) * 2 + ks;
      __builtin_amdgcn_s_setprio(1);
#pragma unroll
      for (int mf = 0; mf < 2; ++mf)
#pragma unroll
        for (int nf = 0; nf < 8; ++nf)
          acc[mf][nf] = __builtin_amdgcn_mfma_f32_16x16x32_bf16(af[mf][ko], bg[nf], acc[mf][nf], 0, 0, 0);
      __builtin_amdgcn_s_setprio(0);
    }

    if (epi) {
#pragma unroll
      for (int nf = 0; nf < 8; ++nf) {
        int colg = C0 + nf * 16 + lr;
        float nbv = nb[nf];
#pragma unroll
        for (int mf = 0; mf < 2; ++mf)
#pragma unroll
          for (int j = 0; j < 4; ++j) {
            int rowg = R0 + w * 32 + mf * 16 + lg * 4 + j;
            float d2 = ncv[mf][j] + nbv - 2.0f * acc[mf][nf][j];
            d2 = fmaxf(d2, 0.0f);
            if ((colg != rowg) && (d2 < bval[mf][j])) {
              bval[mf][j] = d2;
              bcol[mf][j] = colg;
            }
          }
      }
#pragma unroll
      for (int mf = 0; mf < 2; ++mf)
#pragma unroll
        for (int nf = 0; nf < 8; ++nf) acc[mf][nf] = (f32x4){0.f, 0.f, 0.f, 0.f};
    }
    __builtin_amdgcn_s_barrier();
    cur ^= 1;
  }

  // cross-lane reduce over the 16 column lanes, then global combine
#pragma unroll
  for (int mf = 0; mf < 2; ++mf) {
#pragma unroll
    for (int j = 0; j < 4; ++j) {
      unsigned long long pk =
          ((unsigned long long)__builtin_bit_cast(unsigned, bval[mf][j]) << 32) |
          (unsigned)bcol[mf][j];
#pragma unroll
      for (int m = 1; m < 16; m <<= 1) {
        unsigned long long o = __shfl_xor(pk, m, 64);
        if (o < pk) pk = o;
      }
      if (lr == 0) {
        int rowg = R0 + w * 32 + mf * 16 + lg * 4 + j;
        if (rowg < n) atomicMin(&packed[rowg], pk);
      }
    }
  }
}

// ---------- fallback fp32 path (ws too small) ----------
__global__ __launch_bounds__(64) void k_norms(
    const float* __restrict__ x, const int* __restrict__ crow,
    const int* __restrict__ brow, int n, int ncap, float* __restrict__ normc,
    float* __restrict__ normb) {
  int b = blockIdx.x;
  int lane = threadIdx.x;
  bool isC = (b < ncap);
  int j = isC ? b : (b - ncap);
  if (j >= n) {
    if (lane == 0) { if (isC) normc[j] = 0.f; else normb[j] = 3.4e38f; }
    return;
  }
  int row = isC ? crow[j] : brow[j];
  float4 v = ((const float4*)(x + ((size_t)row << 8)))[lane];
  float s = v.x * v.x + v.y * v.y + v.z * v.z + v.w * v.w;
#pragma unroll
  for (int m = 32; m >= 1; m >>= 1) s += __shfl_xor(s, m, 64);
  if (lane == 0) { if (isC) normc[j] = s; else normb[j] = s; }
}

__global__ void k_sample(const int* __restrict__ benign, int n, unsigned span,
                         unsigned k1a, unsigned k1b, unsigned k2a, unsigned k2b,
                         unsigned mult, int* __restrict__ brow) {
  int j = blockIdx.x * blockDim.x + threadIdx.x;
  if (j >= n) return;
  unsigned a0, a1, b0, b1;
  tf2x32(k1a, k1b, 0u, (unsigned)j, &a0, &a1);
  tf2x32(k2a, k2b, 0u, (unsigned)j, &b0, &b1);
  unsigned hi = a0 ^ a1, lo = b0 ^ b1;
  unsigned r = ((hi % span) * mult + (lo % span)) % span;
  brow[j] = benign[r];
}

__global__ __launch_bounds__(256) void k_dist(
    const float* __restrict__ x, const int* __restrict__ crow,
    const int* __restrict__ brow, const float* __restrict__ normc,
    const float* __restrict__ normb, int n, int* __restrict__ neigh) {
  __shared__ float cs[BM][Dims + 4];
  __shared__ float bs[BN][KC + 4];
  const int tid = threadIdx.x;
  const int tx = tid & 15, ty = tid >> 4;
  const int R0 = blockIdx.x * BM;
  const int gra = R0 + ty, grb = R0 + ty + 16;
  for (int k = tid; k < BM * (Dims / 4); k += 256) {
    int r = k >> 6, i4 = k & 63;
    int gr = R0 + r;
    float4 v = make_float4(0.f, 0.f, 0.f, 0.f);
    if (gr < n) v = *(const float4*)(x + (size_t)crow[gr] * Dims + i4 * 4);
    *(float4*)(&cs[r][i4 * 4]) = v;
  }
  float nca = 0.f, ncb = 0.f;
  if (gra < n) nca = normc[gra];
  if (grb < n) ncb = normc[grb];
  float bva = 3.4e38f, bvb = 3.4e38f;
  int bia = 0, bib = 0;
  for (int C0 = 0; C0 < n; C0 += BN) {
    float a00 = 0.f, a01 = 0.f, a10 = 0.f, a11 = 0.f;
    for (int k0 = 0; k0 < Dims; k0 += KC) {
      __syncthreads();
      for (int k = tid; k < BN * (KC / 4); k += 256) {
        int c = k >> 5, i4 = k & 31;
        int gc = C0 + c;
        float4 v = make_float4(0.f, 0.f, 0.f, 0.f);
        if (gc < n) v = *(const float4*)(x + (size_t)brow[gc] * Dims + k0 + i4 * 4);
        *(float4*)(&bs[c][i4 * 4]) = v;
      }
      __syncthreads();
#pragma unroll 8
      for (int i = 0; i < KC; i += 4) {
        float4 ca = *(const float4*)(&cs[ty][k0 + i]);
        float4 cb = *(const float4*)(&cs[ty + 16][k0 + i]);
        float4 ba = *(const float4*)(&bs[tx][i]);
        float4 bb = *(const float4*)(&bs[tx + 16][i]);
        a00 += ca.x * ba.x + ca.y * ba.y + ca.z * ba.z + ca.w * ba.w;
        a01 += ca.x * bb.x + ca.y * bb.y + ca.z * bb.z + ca.w * bb.w;
        a10 += cb.x * ba.x + cb.y * ba.y + cb.z * ba.z + cb.w * ba.w;
        a11 += cb.x * bb.x + cb.y * bb.y + cb.z * bb.z + cb.w * bb.w;
      }
    }
    int gca = C0 + tx, gcb = C0 + tx + 16;
    if (gca < n) {
      float nbv = normb[gca];
      if (gra < n && gca != gra) {
        float d2 = nca + nbv - 2.f * a00;
        if (d2 < bva) { bva = d2; bia = gca; }
      }
      if (grb < n && gca != grb) {
        float d2 = ncb + nbv - 2.f * a10;
        if (d2 < bvb) { bvb = d2; bib = gca; }
      }
    }
    if (gcb < n) {
      float nbv = normb[gcb];
      if (gra < n && gcb != gra) {
        float d2 = nca + nbv - 2.f * a01;
        if (d2 < bva) { bva = d2; bia = gcb; }
      }
      if (grb < n && gcb != grb) {
        float d2 = ncb + nbv - 2.f * a11;
        if (d2 < bvb) { bvb = d2; bib = gcb; }
      }
    }
  }
#pragma unroll
  for (int m = 1; m < 16; m <<= 1) {
    float ov = __shfl_xor(bva, m, 64);
    int oi = __shfl_xor(bia, m, 64);
    if (ov < bva || (ov == bva && oi < bia)) { bva = ov; bia = oi; }
    ov = __shfl_xor(bvb, m, 64);
    oi = __shfl_xor(bib, m, 64);
    if (ov < bvb || (ov == bvb && oi < bib)) { bvb = ov; bib = oi; }
  }
  if (tx == 0) {
    if (gra < n) neigh[gra] = bia;
    if (grb < n) neigh[grb] = bib;
  }
}

// ---------- 4) interpolated synthetic rows ----------
__global__ __launch_bounds__(64) void k_newembed_packed(
    const float* __restrict__ x, const int* __restrict__ crow,
    const int* __restrict__ brow, const unsigned long long* __restrict__ packed,
    int N, float interp, float* __restrict__ out) {
  int r = blockIdx.x;
  int lane = threadIdx.x;
  unsigned long long pk = packed[r];
  int col = (pk == ~0ULL) ? 0 : (int)(unsigned)(pk & 0xffffffffULL);
  const float4* c = (const float4*)(x + (size_t)crow[r] * Dims);
  const float4* b = (const float4*)(x + (size_t)brow[col] * Dims);
  float4 cv = c[lane], bv = b[lane];
  float4 o;
  o.x = cv.x + (bv.x - cv.x) * interp;
  o.y = cv.y + (bv.y - cv.y) * interp;
  o.z = cv.z + (bv.z - cv.z) * interp;
  o.w = cv.w + (bv.w - cv.w) * interp;
  ((float4*)(out + ((size_t)N + r) * Dims))[lane] = o;
}

__global__ __launch_bounds__(64) void k_newembed_int(
    const float* __restrict__ x, const int* __restrict__ crow,
    const int* __restrict__ brow, const int* __restrict__ neigh,
    int N, float interp, float* __restrict__ out) {
  int r = blockIdx.x;
  int lane = threadIdx.x;
  const float4* c = (const float4*)(x + (size_t)crow[r] * Dims);
  const float4* b = (const float4*)(x + (size_t)brow[neigh[r]] * Dims);
  float4 cv = c[lane], bv = b[lane];
  float4 o;
  o.x = cv.x + (bv.x - cv.x) * interp;
  o.y = cv.y + (bv.y - cv.y) * interp;
  o.z = cv.z + (bv.z - cv.z) * interp;
  o.w = cv.w + (bv.w - cv.w) * interp;
  ((float4*)(out + ((size_t)N + r) * Dims))[lane] = o;
}

// ---------- 5) y_out and idx_out tails ----------
__global__ void k_tail(const int* __restrict__ y, const int* __restrict__ idx_train,
                       int N, int NT, int n, float* __restrict__ out) {
  long base2 = (long)(N + n) * Dims;
  long base3 = base2 + (N + n);
  int stride = gridDim.x * blockDim.x;
  for (int k = blockIdx.x * blockDim.x + threadIdx.x; k < N + n; k += stride)
    out[base2 + k] = (k < N) ? (float)y[k] : 1.0f;
  for (int k = blockIdx.x * blockDim.x + threadIdx.x; k < NT + n; k += stride)
    out[base3 + k] = (k < NT) ? (float)idx_train[k] : (float)(N + (k - NT));
}

extern "C" void kernel_launch(void* const* d_in, const int* in_sizes, int n_in,
                              void* d_out, int out_size, void* d_ws, size_t ws_size,
                              hipStream_t stream) {
  const float* x = (const float*)d_in[0];
  const int* y = (const int*)d_in[1];
  const int* idx_train = (const int*)d_in[2];
  float* out = (float*)d_out;
  const int N = in_sizes[1];
  const int NT = in_sizes[2];

  long nl = ((long)out_size - ((long)N * Dims + N + NT)) / (Dims + 2);
  int n = (int)nl;
  if (n < 0) n = 0;
  if (n > NT) n = NT;
  int nb = NT - n;
  int ncap = (n + 127) & ~127;
  if (ncap < 128) ncap = 128;

  size_t cap = ((size_t)NT + 255) & ~(size_t)255;
  int* chosen = (int*)d_ws;
  int* benign = chosen + cap;
  int* brow = benign + cap;
  int* neigh = brow + cap;
  float* normc = (float*)(neigh + cap);
  float* normb = normc + cap;
  unsigned long long* packed = (unsigned long long*)(normb + cap);
  unsigned short* Cb = (unsigned short*)(packed + ncap);
  unsigned short* Bb = Cb + (size_t)ncap * 256;
  size_t need = (char*)(Bb + (size_t)ncap * 256) - (char*)d_ws;
  bool use_mfma = (ws_size >= need);

  // Host-side JAX threefry derivations from key(42)
  unsigned s0_, s1_, t0_, t1_;
  tf2x32(0u, 42u, 0u, 0u, &s0_, &s1_);
  tf2x32(0u, 42u, 0u, 1u, &t0_, &t1_);
  unsigned i0_, i1_;
  tf2x32(t0_, t1_, 0u, 0u, &i0_, &i1_);
  unsigned ub = i0_ ^ i1_;
  float interp;
  { unsigned uu = (ub >> 9) | 0x3f800000u; memcpy(&interp, &uu, 4); interp -= 1.0f; }
  unsigned k1a, k1b, k2a, k2b;
  { unsigned a, b; tf2x32(s0_, s1_, 0u, 0u, &a, &b); k1a = a; k1b = b; }
  { unsigned a, b; tf2x32(s0_, s1_, 0u, 1u, &a, &b); k2a = a; k2b = b; }
  unsigned span = (nb > 0) ? (unsigned)nb : 1u;
  unsigned m0 = 65536u % span;
  unsigned mult = (m0 * m0) % span;

  k_compact<<<1, 1024, 0, stream>>>(idx_train, y, NT, chosen, benign);
  if (n > 0 && nb > 0) {
    if (use_mfma) {
      k_prep<<<2 * ncap, 64, 0, stream>>>(x, chosen, benign, n, ncap, span,
                                          k1a, k1b, k2a, k2b, mult,
                                          Cb, Bb, brow, normc, normb, packed);
      dim3 grid(ncap / 128, NSEG);
      k_mdist<<<grid, 256, 0, stream>>>(Cb, Bb, normc, normb, n, ncap, packed);
    } else {
      k_sample<<<(n + 255) / 256, 256, 0, stream>>>(benign, n, span, k1a, k1b, k2a, k2b, mult, brow);
      k_norms<<<2 * ncap, 64, 0, stream>>>(x, chosen, brow, n, ncap, normc, normb);
      k_dist<<<(n + BM - 1) / BM, 256, 0, stream>>>(x, chosen, brow, normc, normb, n, neigh);
    }
  }
  hipMemcpyAsync(out, x, (size_t)N * Dims * sizeof(float), hipMemcpyDeviceToDevice, stream);
  if (n > 0 && nb > 0) {
    if (use_mfma)
      k_newembed_packed<<<n, 64, 0, stream>>>(x, chosen, brow, packed, N, interp, out);
    else
      k_newembed_int<<<n, 64, 0, stream>>>(x, chosen, brow, neigh, N, interp, out);
  }
  k_tail<<<512, 256, 0, stream>>>(y, idx_train, N, NT, n, out);
}

// Round 4
// 481.986 us; speedup vs baseline: 1.0149x; 1.0149x over previous
//
#include <hip/hip_runtime.h>
#include <string.h>

#define Dims 256
#define BM 32
#define BN 32
#define KC 128
#define NSEG 8
#define BIAS 2048.0f

typedef short bf16x8 __attribute__((ext_vector_type(8)));
typedef float f32x4 __attribute__((ext_vector_type(4)));

// ---------- Threefry2x32 (JAX), usable host+device ----------
__host__ __device__ inline void tf2x32(unsigned k0, unsigned k1,
                                       unsigned x0, unsigned x1,
                                       unsigned* o0, unsigned* o1) {
  unsigned ks[3] = {k0, k1, k0 ^ k1 ^ 0x1BD11BDAu};
  x0 += ks[0]; x1 += ks[1];
  const unsigned rA[4] = {13u, 15u, 26u, 6u};
  const unsigned rB[4] = {17u, 29u, 16u, 24u};
#pragma unroll
  for (int g = 0; g < 5; ++g) {
    const unsigned* rr = (g & 1) ? rB : rA;
#pragma unroll
    for (int j = 0; j < 4; ++j) {
      x0 += x1;
      x1 = (x1 << rr[j]) | (x1 >> (32u - rr[j]));
      x1 ^= x0;
    }
    x0 += ks[(g + 1) % 3];
    x1 += ks[(g + 2) % 3] + (unsigned)(g + 1);
  }
  *o0 = x0; *o1 = x1;
}

__device__ inline unsigned short f2bf(float f) {
  unsigned u = __builtin_bit_cast(unsigned, f);
  unsigned r = (u + 0x7fffu + ((u >> 16) & 1u)) >> 16;
  return (unsigned short)r;
}

// ---------- 1) stable compaction ----------
__global__ __launch_bounds__(1024) void k_compact(
    const int* __restrict__ idx_train, const int* __restrict__ y, int NT,
    int* __restrict__ chosen, int* __restrict__ benign) {
  __shared__ int wsum1[16], wsum0[16], woff1[16], woff0[16];
  int t = threadIdx.x;
  int lane = t & 63, w = t >> 6;
  int ept = (NT + 1023) >> 10;
  int base = t * ept;
  int n1 = 0, n0 = 0;
  for (int k = 0; k < ept; ++k) {
    int e = base + k;
    if (e < NT) {
      int idx = idx_train[e];
      if (y[idx] == 1) n1++; else n0++;
    }
  }
  int s1 = n1, s0 = n0;
#pragma unroll
  for (int d = 1; d < 64; d <<= 1) {
    int v1 = __shfl_up(s1, d, 64);
    int v0 = __shfl_up(s0, d, 64);
    if (lane >= d) { s1 += v1; s0 += v0; }
  }
  if (lane == 63) { wsum1[w] = s1; wsum0[w] = s0; }
  __syncthreads();
  if (t == 0) {
    int a = 0, b = 0;
    for (int i = 0; i < 16; ++i) {
      woff1[i] = a; a += wsum1[i];
      woff0[i] = b; b += wsum0[i];
    }
  }
  __syncthreads();
  int p1 = woff1[w] + s1 - n1;
  int p0 = woff0[w] + s0 - n0;
  for (int k = 0; k < ept; ++k) {
    int e = base + k;
    if (e < NT) {
      int idx = idx_train[e];
      if (y[idx] == 1) chosen[p1++] = idx; else benign[p0++] = idx;
    }
  }
}

// ---------- 2) fused sample + gather + bf16 convert + norms + key init ----------
__global__ __launch_bounds__(256) void k_prep(
    const float* __restrict__ x, const int* __restrict__ chosen,
    const int* __restrict__ benign, int n, int ncap,
    unsigned span, unsigned k1a, unsigned k1b, unsigned k2a, unsigned k2b,
    unsigned mult, unsigned short* __restrict__ Cb, unsigned short* __restrict__ Bb,
    int* __restrict__ brow, float* __restrict__ normb,
    unsigned* __restrict__ packed) {
  int g = blockIdx.x * 4 + (threadIdx.x >> 6);
  int lane = threadIdx.x & 63;
  bool isC = (g < ncap);
  int j = isC ? g : (g - ncap);
  if (isC && lane == 0) packed[j] = 0xFFFFFFFFu;
  unsigned short* dst = (isC ? Cb : Bb) + ((size_t)j << 8) + lane * 4;
  if (j >= n) {
    *(ushort4*)dst = (ushort4){0, 0, 0, 0};
    if (!isC && lane == 0) normb[j] = 3.4e38f;
    return;
  }
  int row;
  if (isC) {
    row = chosen[j];
  } else {
    unsigned a0, a1, b0, b1;
    tf2x32(k1a, k1b, 0u, (unsigned)j, &a0, &a1);
    tf2x32(k2a, k2b, 0u, (unsigned)j, &b0, &b1);
    unsigned hi = a0 ^ a1, lo = b0 ^ b1;
    unsigned r = ((hi % span) * mult + (lo % span)) % span;
    row = benign[r];
    if (lane == 0) brow[j] = row;
  }
  float4 v = ((const float4*)(x + ((size_t)row << 8)))[lane];
  ushort4 o;
  o.x = f2bf(v.x); o.y = f2bf(v.y); o.z = f2bf(v.z); o.w = f2bf(v.w);
  *(ushort4*)dst = o;
  if (!isC) {
    float s = v.x * v.x + v.y * v.y + v.z * v.z + v.w * v.w;
#pragma unroll
    for (int m = 32; m >= 1; m >>= 1) s += __shfl_xor(s, m, 64);
    if (lane == 0) normb[j] = s;
  }
}

// ---------- 3) MFMA distance + fused argmin: A-in-regs, B global->regs, no LDS ----------
__global__ __launch_bounds__(256, 2) void k_mdist(
    const unsigned short* __restrict__ Cb, const unsigned short* __restrict__ Bb,
    const float* __restrict__ normb,
    int n, int ncap, unsigned* __restrict__ packed) {
  const int tid = threadIdx.x;
  const int l = tid & 63;
  const int w = tid >> 6;            // column group 0..3 (32 cols of the 128-col tile)
  const int lr = l & 15, lg = l >> 4;
  const int R0 = blockIdx.x * 64;
  const int ntiles = ncap >> 7;
  const int per = (ntiles + NSEG - 1) / NSEG;
  const int t0 = blockIdx.y * per;
  int t1 = t0 + per; if (t1 > ntiles) t1 = ntiles;
  if (t0 >= t1) return;

  // A fragments for rows R0..R0+63 held in registers for the whole kernel
  bf16x8 af[4][8];
  {
    const char* Ab = (const char*)Cb + (((size_t)R0 + lr) << 9) + lg * 16;
#pragma unroll
    for (int mf = 0; mf < 4; ++mf)
#pragma unroll
      for (int ko = 0; ko < 8; ++ko)
        af[mf][ko] = *(const bf16x8*)(Ab + (size_t)mf * (16 * 512) + ko * 64);
  }

  unsigned key[4][4];
#pragma unroll
  for (int mf = 0; mf < 4; ++mf)
#pragma unroll
    for (int j = 0; j < 4; ++j) key[mf][j] = 0xFFFFFFFFu;

  const int rowbase = R0 + lg * 4;   // + mf*16 + j
  const char* Bl = (const char*)Bb + (((size_t)(w * 32 + lr)) << 9) + lg * 16;

  bf16x8 pa[2][2], pb[2][2];

#define LQ(buf, ct, q)                                                   \
  {                                                                      \
    const char* _b = Bl + (((size_t)(ct)) << 16) + (q) * 128;            \
    buf[0][0] = *(const bf16x8*)(_b);                                    \
    buf[0][1] = *(const bf16x8*)(_b + 64);                               \
    buf[1][0] = *(const bf16x8*)(_b + 16 * 512);                         \
    buf[1][1] = *(const bf16x8*)(_b + 16 * 512 + 64);                    \
  }

#define MQ(buf, q)                                                       \
  {                                                                      \
    _Pragma("unroll") for (int kk = 0; kk < 2; ++kk)                     \
      _Pragma("unroll") for (int mf = 0; mf < 4; ++mf)                   \
        _Pragma("unroll") for (int nf = 0; nf < 2; ++nf)                 \
          acc[mf][nf] = __builtin_amdgcn_mfma_f32_16x16x32_bf16(         \
              af[mf][(q) * 2 + kk], buf[nf][kk], acc[mf][nf], 0, 0, 0);  \
  }

  LQ(pa, t0, 0);
  for (int ct = t0; ct < t1; ++ct) {
    const int C0 = ct << 7;
    float nbB0 = normb[C0 + w * 32 + lr] + BIAS;
    float nbB1 = normb[C0 + w * 32 + 16 + lr] + BIAS;
    f32x4 acc[4][2];
#pragma unroll
    for (int mf = 0; mf < 4; ++mf)
#pragma unroll
      for (int nf = 0; nf < 2; ++nf) acc[mf][nf] = (f32x4){0.f, 0.f, 0.f, 0.f};

    LQ(pb, ct, 1); MQ(pa, 0);
    LQ(pa, ct, 2); MQ(pb, 1);
    LQ(pb, ct, 3); MQ(pa, 2);
    if (ct + 1 < t1) LQ(pa, ct + 1, 0);
    MQ(pb, 3);

    // epilogue: m = nb + BIAS - 2*dot (per-row ||c||^2 dropped: argmin-invariant);
    // splice 14-bit col into low mantissa bits, track u32 min.
    const int colg0 = C0 + w * 32 + lr;
    const int colg1 = colg0 + 16;
    const bool ovl = (R0 + 64 > C0) && (R0 < C0 + 128);
#pragma unroll
    for (int mf = 0; mf < 4; ++mf) {
#pragma unroll
      for (int j = 0; j < 4; ++j) {
        float m0 = fmaf(acc[mf][0][j], -2.0f, nbB0);
        float m1 = fmaf(acc[mf][1][j], -2.0f, nbB1);
        unsigned q0 = (__builtin_bit_cast(unsigned, m0) & 0xFFFFC000u) | (unsigned)colg0;
        unsigned q1 = (__builtin_bit_cast(unsigned, m1) & 0xFFFFC000u) | (unsigned)colg1;
        if (ovl) {
          int rowg = rowbase + mf * 16 + j;
          if (colg0 == rowg) q0 = 0xFFFFFFFFu;
          if (colg1 == rowg) q1 = 0xFFFFFFFFu;
        }
        unsigned km = q0 < q1 ? q0 : q1;
        if (km < key[mf][j]) key[mf][j] = km;
      }
    }
  }
#undef LQ
#undef MQ

  // reduce across the 16 column-lanes, then global combine
#pragma unroll
  for (int mf = 0; mf < 4; ++mf) {
#pragma unroll
    for (int j = 0; j < 4; ++j) {
      unsigned k = key[mf][j];
#pragma unroll
      for (int m = 1; m < 16; m <<= 1) {
        unsigned o = __shfl_xor(k, m, 64);
        k = (o < k) ? o : k;
      }
      if (lr == 0) {
        int rowg = rowbase + mf * 16 + j;
        if (rowg < n) atomicMin(&packed[rowg], k);
      }
    }
  }
}

// ---------- 4) fused new_embed + y/idx tails ----------
__global__ __launch_bounds__(256) void k_final(
    const float* __restrict__ x, const int* __restrict__ crow,
    const int* __restrict__ brow, const unsigned* __restrict__ packed,
    const int* __restrict__ y, const int* __restrict__ idx_train,
    int N, int NT, int n, float interp, float* __restrict__ out) {
  int nb4 = (n + 3) >> 2;
  if ((int)blockIdx.x < nb4) {
    int r = blockIdx.x * 4 + (threadIdx.x >> 6);
    int lane = threadIdx.x & 63;
    if (r < n) {
      int col = (int)(packed[r] & 0x3FFFu);
      const float4* c = (const float4*)(x + ((size_t)crow[r] << 8));
      const float4* b = (const float4*)(x + ((size_t)brow[col] << 8));
      float4 cv = c[lane], bv = b[lane];
      float4 o;
      o.x = cv.x + (bv.x - cv.x) * interp;
      o.y = cv.y + (bv.y - cv.y) * interp;
      o.z = cv.z + (bv.z - cv.z) * interp;
      o.w = cv.w + (bv.w - cv.w) * interp;
      ((float4*)(out + ((size_t)N + r) * Dims))[lane] = o;
    }
    return;
  }
  long base2 = (long)(N + n) * Dims;
  long base3 = base2 + (N + n);
  int nblk = gridDim.x - nb4;
  int stride = nblk * 256;
  int start = (blockIdx.x - nb4) * 256 + threadIdx.x;
  for (int k = start; k < N + n; k += stride)
    out[base2 + k] = (k < N) ? (float)y[k] : 1.0f;
  for (int k = start; k < NT + n; k += stride)
    out[base3 + k] = (k < NT) ? (float)idx_train[k] : (float)(N + (k - NT));
}

// ---------- fallback fp32 path (ws too small / ncap too large) ----------
__global__ void k_sample(const int* __restrict__ benign, int n, unsigned span,
                         unsigned k1a, unsigned k1b, unsigned k2a, unsigned k2b,
                         unsigned mult, int* __restrict__ brow) {
  int j = blockIdx.x * blockDim.x + threadIdx.x;
  if (j >= n) return;
  unsigned a0, a1, b0, b1;
  tf2x32(k1a, k1b, 0u, (unsigned)j, &a0, &a1);
  tf2x32(k2a, k2b, 0u, (unsigned)j, &b0, &b1);
  unsigned hi = a0 ^ a1, lo = b0 ^ b1;
  unsigned r = ((hi % span) * mult + (lo % span)) % span;
  brow[j] = benign[r];
}

__global__ __launch_bounds__(64) void k_norms(
    const float* __restrict__ x, const int* __restrict__ crow,
    const int* __restrict__ brow, int n, int ncap, float* __restrict__ normc,
    float* __restrict__ normb) {
  int b = blockIdx.x;
  int lane = threadIdx.x;
  bool isC = (b < ncap);
  int j = isC ? b : (b - ncap);
  if (j >= n) {
    if (lane == 0) { if (isC) normc[j] = 0.f; else normb[j] = 3.4e38f; }
    return;
  }
  int row = isC ? crow[j] : brow[j];
  float4 v = ((const float4*)(x + ((size_t)row << 8)))[lane];
  float s = v.x * v.x + v.y * v.y + v.z * v.z + v.w * v.w;
#pragma unroll
  for (int m = 32; m >= 1; m >>= 1) s += __shfl_xor(s, m, 64);
  if (lane == 0) { if (isC) normc[j] = s; else normb[j] = s; }
}

__global__ __launch_bounds__(256) void k_dist(
    const float* __restrict__ x, const int* __restrict__ crow,
    const int* __restrict__ brow, const float* __restrict__ normc,
    const float* __restrict__ normb, int n, int* __restrict__ neigh) {
  __shared__ float cs[BM][Dims + 4];
  __shared__ float bs[BN][KC + 4];
  const int tid = threadIdx.x;
  const int tx = tid & 15, ty = tid >> 4;
  const int R0 = blockIdx.x * BM;
  const int gra = R0 + ty, grb = R0 + ty + 16;
  for (int k = tid; k < BM * (Dims / 4); k += 256) {
    int r = k >> 6, i4 = k & 63;
    int gr = R0 + r;
    float4 v = make_float4(0.f, 0.f, 0.f, 0.f);
    if (gr < n) v = *(const float4*)(x + (size_t)crow[gr] * Dims + i4 * 4);
    *(float4*)(&cs[r][i4 * 4]) = v;
  }
  float nca = 0.f, ncb = 0.f;
  if (gra < n) nca = normc[gra];
  if (grb < n) ncb = normc[grb];
  float bva = 3.4e38f, bvb = 3.4e38f;
  int bia = 0, bib = 0;
  for (int C0 = 0; C0 < n; C0 += BN) {
    float a00 = 0.f, a01 = 0.f, a10 = 0.f, a11 = 0.f;
    for (int k0 = 0; k0 < Dims; k0 += KC) {
      __syncthreads();
      for (int k = tid; k < BN * (KC / 4); k += 256) {
        int c = k >> 5, i4 = k & 31;
        int gc = C0 + c;
        float4 v = make_float4(0.f, 0.f, 0.f, 0.f);
        if (gc < n) v = *(const float4*)(x + (size_t)brow[gc] * Dims + k0 + i4 * 4);
        *(float4*)(&bs[c][i4 * 4]) = v;
      }
      __syncthreads();
#pragma unroll 8
      for (int i = 0; i < KC; i += 4) {
        float4 ca = *(const float4*)(&cs[ty][k0 + i]);
        float4 cb = *(const float4*)(&cs[ty + 16][k0 + i]);
        float4 ba = *(const float4*)(&bs[tx][i]);
        float4 bb = *(const float4*)(&bs[tx + 16][i]);
        a00 += ca.x * ba.x + ca.y * ba.y + ca.z * ba.z + ca.w * ba.w;
        a01 += ca.x * bb.x + ca.y * bb.y + ca.z * bb.z + ca.w * bb.w;
        a10 += cb.x * ba.x + cb.y * ba.y + cb.z * ba.z + cb.w * ba.w;
        a11 += cb.x * bb.x + cb.y * bb.y + cb.z * bb.z + cb.w * bb.w;
      }
    }
    int gca = C0 + tx, gcb = C0 + tx + 16;
    if (gca < n) {
      float nbv = normb[gca];
      if (gra < n && gca != gra) {
        float d2 = nca + nbv - 2.f * a00;
        if (d2 < bva) { bva = d2; bia = gca; }
      }
      if (grb < n && gca != grb) {
        float d2 = ncb + nbv - 2.f * a10;
        if (d2 < bvb) { bvb = d2; bib = gca; }
      }
    }
    if (gcb < n) {
      float nbv = normb[gcb];
      if (gra < n && gcb != gra) {
        float d2 = nca + nbv - 2.f * a01;
        if (d2 < bva) { bva = d2; bia = gcb; }
      }
      if (grb < n && gcb != grb) {
        float d2 = ncb + nbv - 2.f * a11;
        if (d2 < bvb) { bvb = d2; bib = gcb; }
      }
    }
  }
#pragma unroll
  for (int m = 1; m < 16; m <<= 1) {
    float ov = __shfl_xor(bva, m, 64);
    int oi = __shfl_xor(bia, m, 64);
    if (ov < bva || (ov == bva && oi < bia)) { bva = ov; bia = oi; }
    ov = __shfl_xor(bvb, m, 64);
    oi = __shfl_xor(bib, m, 64);
    if (ov < bvb || (ov == bvb && oi < bib)) { bvb = ov; bib = oi; }
  }
  if (tx == 0) {
    if (gra < n) neigh[gra] = bia;
    if (grb < n) neigh[grb] = bib;
  }
}

__global__ __launch_bounds__(64) void k_newembed_int(
    const float* __restrict__ x, const int* __restrict__ crow,
    const int* __restrict__ brow, const int* __restrict__ neigh,
    int N, float interp, float* __restrict__ out) {
  int r = blockIdx.x;
  int lane = threadIdx.x;
  const float4* c = (const float4*)(x + (size_t)crow[r] * Dims);
  const float4* b = (const float4*)(x + (size_t)brow[neigh[r]] * Dims);
  float4 cv = c[lane], bv = b[lane];
  float4 o;
  o.x = cv.x + (bv.x - cv.x) * interp;
  o.y = cv.y + (bv.y - cv.y) * interp;
  o.z = cv.z + (bv.z - cv.z) * interp;
  o.w = cv.w + (bv.w - cv.w) * interp;
  ((float4*)(out + ((size_t)N + r) * Dims))[lane] = o;
}

__global__ void k_tail(const int* __restrict__ y, const int* __restrict__ idx_train,
                       int N, int NT, int n, float* __restrict__ out) {
  long base2 = (long)(N + n) * Dims;
  long base3 = base2 + (N + n);
  int stride = gridDim.x * blockDim.x;
  for (int k = blockIdx.x * blockDim.x + threadIdx.x; k < N + n; k += stride)
    out[base2 + k] = (k < N) ? (float)y[k] : 1.0f;
  for (int k = blockIdx.x * blockDim.x + threadIdx.x; k < NT + n; k += stride)
    out[base3 + k] = (k < NT) ? (float)idx_train[k] : (float)(N + (k - NT));
}

extern "C" void kernel_launch(void* const* d_in, const int* in_sizes, int n_in,
                              void* d_out, int out_size, void* d_ws, size_t ws_size,
                              hipStream_t stream) {
  const float* x = (const float*)d_in[0];
  const int* y = (const int*)d_in[1];
  const int* idx_train = (const int*)d_in[2];
  float* out = (float*)d_out;
  const int N = in_sizes[1];
  const int NT = in_sizes[2];

  long nl = ((long)out_size - ((long)N * Dims + N + NT)) / (Dims + 2);
  int n = (int)nl;
  if (n < 0) n = 0;
  if (n > NT) n = NT;
  int nb = NT - n;
  int ncap = (n + 127) & ~127;
  if (ncap < 128) ncap = 128;

  size_t cap = ((size_t)NT + 255) & ~(size_t)255;
  int* chosen = (int*)d_ws;
  int* benign = chosen + cap;
  int* brow = benign + cap;
  int* neigh = brow + cap;
  float* normc = (float*)(neigh + cap);
  float* normb = normc + cap;
  unsigned* packed = (unsigned*)(normb + cap);
  unsigned short* Cb = (unsigned short*)(packed + ((ncap + 255) & ~255));
  unsigned short* Bb = Cb + (size_t)ncap * 256;
  size_t need = (char*)(Bb + (size_t)ncap * 256) - (char*)d_ws;
  bool use_mfma = (ws_size >= need) && (ncap <= 16384);

  // Host-side JAX threefry derivations from key(42)
  unsigned s0_, s1_, t0_, t1_;
  tf2x32(0u, 42u, 0u, 0u, &s0_, &s1_);
  tf2x32(0u, 42u, 0u, 1u, &t0_, &t1_);
  unsigned i0_, i1_;
  tf2x32(t0_, t1_, 0u, 0u, &i0_, &i1_);
  unsigned ub = i0_ ^ i1_;
  float interp;
  { unsigned uu = (ub >> 9) | 0x3f800000u; memcpy(&interp, &uu, 4); interp -= 1.0f; }
  unsigned k1a, k1b, k2a, k2b;
  { unsigned a, b; tf2x32(s0_, s1_, 0u, 0u, &a, &b); k1a = a; k1b = b; }
  { unsigned a, b; tf2x32(s0_, s1_, 0u, 1u, &a, &b); k2a = a; k2b = b; }
  unsigned span = (nb > 0) ? (unsigned)nb : 1u;
  unsigned m0 = 65536u % span;
  unsigned mult = (m0 * m0) % span;

  k_compact<<<1, 1024, 0, stream>>>(idx_train, y, NT, chosen, benign);
  if (n > 0 && nb > 0) {
    if (use_mfma) {
      k_prep<<<(2 * ncap) / 4, 256, 0, stream>>>(x, chosen, benign, n, ncap, span,
                                                 k1a, k1b, k2a, k2b, mult,
                                                 Cb, Bb, brow, normb, packed);
      dim3 grid(ncap / 64, NSEG);
      k_mdist<<<grid, 256, 0, stream>>>(Cb, Bb, normb, n, ncap, packed);
    } else {
      k_sample<<<(n + 255) / 256, 256, 0, stream>>>(benign, n, span, k1a, k1b, k2a, k2b, mult, brow);
      k_norms<<<2 * ncap, 64, 0, stream>>>(x, chosen, brow, n, ncap, normc, normb);
      k_dist<<<(n + BM - 1) / BM, 256, 0, stream>>>(x, chosen, brow, normc, normb, n, neigh);
    }
  }
  hipMemcpyAsync(out, x, (size_t)N * Dims * sizeof(float), hipMemcpyDeviceToDevice, stream);
  if (n > 0 && nb > 0) {
    if (use_mfma) {
      int nb4 = (n + 3) >> 2;
      k_final<<<nb4 + 128, 256, 0, stream>>>(x, chosen, brow, packed, y, idx_train,
                                             N, NT, n, interp, out);
    } else {
      k_newembed_int<<<n, 64, 0, stream>>>(x, chosen, brow, neigh, N, interp, out);
      k_tail<<<512, 256, 0, stream>>>(y, idx_train, N, NT, n, out);
    }
  } else {
    k_tail<<<512, 256, 0, stream>>>(y, idx_train, N, NT, n, out);
  }
}

// Round 5
// 425.384 us; speedup vs baseline: 1.1499x; 1.1331x over previous
//
#include <hip/hip_runtime.h>
#include <string.h>

#define Dims 256
#define BM 32
#define BN 32
#define KC 128
#define NSEG 8
#define BIAS 2048.0f

typedef short bf16x8 __attribute__((ext_vector_type(8)));
typedef float f32x4 __attribute__((ext_vector_type(4)));

// ---------- Threefry2x32 (JAX), usable host+device ----------
__host__ __device__ inline void tf2x32(unsigned k0, unsigned k1,
                                       unsigned x0, unsigned x1,
                                       unsigned* o0, unsigned* o1) {
  unsigned ks[3] = {k0, k1, k0 ^ k1 ^ 0x1BD11BDAu};
  x0 += ks[0]; x1 += ks[1];
  const unsigned rA[4] = {13u, 15u, 26u, 6u};
  const unsigned rB[4] = {17u, 29u, 16u, 24u};
#pragma unroll
  for (int g = 0; g < 5; ++g) {
    const unsigned* rr = (g & 1) ? rB : rA;
#pragma unroll
    for (int j = 0; j < 4; ++j) {
      x0 += x1;
      x1 = (x1 << rr[j]) | (x1 >> (32u - rr[j]));
      x1 ^= x0;
    }
    x0 += ks[(g + 1) % 3];
    x1 += ks[(g + 2) % 3] + (unsigned)(g + 1);
  }
  *o0 = x0; *o1 = x1;
}

__device__ inline unsigned short f2bf(float f) {
  unsigned u = __builtin_bit_cast(unsigned, f);
  unsigned r = (u + 0x7fffu + ((u >> 16) & 1u)) >> 16;
  return (unsigned short)r;
}

// ---------- 1) stable compaction ----------
__global__ __launch_bounds__(1024) void k_compact(
    const int* __restrict__ idx_train, const int* __restrict__ y, int NT,
    int* __restrict__ chosen, int* __restrict__ benign) {
  __shared__ int wsum1[16], wsum0[16], woff1[16], woff0[16];
  int t = threadIdx.x;
  int lane = t & 63, w = t >> 6;
  int ept = (NT + 1023) >> 10;
  int base = t * ept;
  int n1 = 0, n0 = 0;
  for (int k = 0; k < ept; ++k) {
    int e = base + k;
    if (e < NT) {
      int idx = idx_train[e];
      if (y[idx] == 1) n1++; else n0++;
    }
  }
  int s1 = n1, s0 = n0;
#pragma unroll
  for (int d = 1; d < 64; d <<= 1) {
    int v1 = __shfl_up(s1, d, 64);
    int v0 = __shfl_up(s0, d, 64);
    if (lane >= d) { s1 += v1; s0 += v0; }
  }
  if (lane == 63) { wsum1[w] = s1; wsum0[w] = s0; }
  __syncthreads();
  if (t == 0) {
    int a = 0, b = 0;
    for (int i = 0; i < 16; ++i) {
      woff1[i] = a; a += wsum1[i];
      woff0[i] = b; b += wsum0[i];
    }
  }
  __syncthreads();
  int p1 = woff1[w] + s1 - n1;
  int p0 = woff0[w] + s0 - n0;
  for (int k = 0; k < ept; ++k) {
    int e = base + k;
    if (e < NT) {
      int idx = idx_train[e];
      if (y[idx] == 1) chosen[p1++] = idx; else benign[p0++] = idx;
    }
  }
}

// ---------- 2) fused sample + gather + bf16 convert + norms + key init ----------
__global__ __launch_bounds__(256) void k_prep(
    const float* __restrict__ x, const int* __restrict__ chosen,
    const int* __restrict__ benign, int n, int ncap,
    unsigned span, unsigned k1a, unsigned k1b, unsigned k2a, unsigned k2b,
    unsigned mult, unsigned short* __restrict__ Cb, unsigned short* __restrict__ Bb,
    int* __restrict__ brow, float* __restrict__ normb,
    unsigned* __restrict__ packed) {
  int g = blockIdx.x * 4 + (threadIdx.x >> 6);
  int lane = threadIdx.x & 63;
  bool isC = (g < ncap);
  int j = isC ? g : (g - ncap);
  if (isC && lane == 0) packed[j] = 0xFFFFFFFFu;
  unsigned short* dst = (isC ? Cb : Bb) + ((size_t)j << 8) + lane * 4;
  if (j >= n) {
    *(ushort4*)dst = (ushort4){0, 0, 0, 0};
    if (!isC && lane == 0) normb[j] = 3.4e38f;
    return;
  }
  int row;
  if (isC) {
    row = chosen[j];
  } else {
    unsigned a0, a1, b0, b1;
    tf2x32(k1a, k1b, 0u, (unsigned)j, &a0, &a1);
    tf2x32(k2a, k2b, 0u, (unsigned)j, &b0, &b1);
    unsigned hi = a0 ^ a1, lo = b0 ^ b1;
    unsigned r = ((hi % span) * mult + (lo % span)) % span;
    row = benign[r];
    if (lane == 0) brow[j] = row;
  }
  float4 v = ((const float4*)(x + ((size_t)row << 8)))[lane];
  ushort4 o;
  o.x = f2bf(v.x); o.y = f2bf(v.y); o.z = f2bf(v.z); o.w = f2bf(v.w);
  *(ushort4*)dst = o;
  if (!isC) {
    float s = v.x * v.x + v.y * v.y + v.z * v.z + v.w * v.w;
#pragma unroll
    for (int m = 32; m >= 1; m >>= 1) s += __shfl_xor(s, m, 64);
    if (lane == 0) normb[j] = s;
  }
}

// ---------- 3) MFMA distance + argmin: 256-row blocks, A in regs, B via swizzled LDS ----------
__global__ __launch_bounds__(256, 2) void k_mdist(
    const unsigned short* __restrict__ Cb, const unsigned short* __restrict__ Bb,
    const float* __restrict__ normb,
    int n, int ncap, unsigned* __restrict__ packed) {
  __shared__ __align__(16) char Bs[2][32768];   // [buf][64 cols * 512B], XOR-swizzled slots
  const int tid = threadIdx.x;
  const int l = tid & 63;
  const int w = tid >> 6;          // row group: wave owns rows R0+w*64 .. +63
  const int lr = l & 15, lg = l >> 4;
  const int R0 = blockIdx.x * 256;
  const int ntiles = ncap >> 6;    // 64-col tiles
  const int per = (ntiles + NSEG - 1) / NSEG;
  const int t0 = blockIdx.y * per;
  int t1 = t0 + per; if (t1 > ntiles) t1 = ntiles;
  if (t0 >= t1) return;

  // staging geometry: thread handles cols sc and sc+32; 16B chunk sq, rows of 512B
  const int sc = tid >> 3;
  const int sq = tid & 7;
  const int scw = sc & 7;          // (sc+32)&7 == sc&7

  uint4 sreg[4];
#define SLOADH(ct, half)                                                        \
  {                                                                             \
    const char* sb = (const char*)Bb + ((size_t)(ct) << 15) +                   \
                     (size_t)(sc + (half) * 32) * 512 + sq * 16;                \
    _Pragma("unroll") for (int i = 0; i < 4; ++i)                               \
        sreg[i] = *(const uint4*)(sb + i * 128);                                \
  }
#define SWRITEH(buf, half)                                                      \
  {                                                                             \
    char* db = Bs[buf] + (sc + (half) * 32) * 512;                              \
    _Pragma("unroll") for (int i = 0; i < 4; ++i)                               \
        *(uint4*)(db + (((sq + i * 8) ^ scw) << 4)) = sreg[i];                  \
  }

  // prologue: issue first B half-tiles and A-panel loads, then write + barrier
  SLOADH(t0, 0);
  bf16x8 af[4][8];
  {
    const char* Ab = (const char*)Cb + (((size_t)(R0 + w * 64 + lr)) << 9) + lg * 16;
#pragma unroll
    for (int mf = 0; mf < 4; ++mf)
#pragma unroll
      for (int ko = 0; ko < 8; ++ko)
        af[mf][ko] = *(const bf16x8*)(Ab + mf * 8192 + ko * 64);
  }
  asm volatile("s_waitcnt vmcnt(0)" ::: "memory");
  SWRITEH(0, 0);
  SLOADH(t0, 1);
  asm volatile("s_waitcnt vmcnt(0)" ::: "memory");
  SWRITEH(0, 1);
  __syncthreads();

  unsigned key[4][4];
#pragma unroll
  for (int mf = 0; mf < 4; ++mf)
#pragma unroll
    for (int j = 0; j < 4; ++j) key[mf][j] = 0xFFFFFFFFu;

  const int rowbase = R0 + w * 64 + lg * 4;  // + mf*16 + j

  int cur = 0;
  for (int ct = t0; ct < t1; ++ct) {
    const int C0 = ct << 6;
    const bool more = (ct + 1 < t1);
    const int nxt = cur ^ 1;

    if (more) SLOADH(ct + 1, 0);
    float nb[4];
#pragma unroll
    for (int nf = 0; nf < 4; ++nf) nb[nf] = normb[C0 + nf * 16 + lr] + BIAS;

    f32x4 acc[4][4];
#pragma unroll
    for (int mf = 0; mf < 4; ++mf)
#pragma unroll
      for (int nf = 0; nf < 4; ++nf) acc[mf][nf] = (f32x4){0.f, 0.f, 0.f, 0.f};

    const char* Bbuf = Bs[cur];
#pragma unroll
    for (int ko = 0; ko < 4; ++ko) {
      bf16x8 bf[4];
#pragma unroll
      for (int nf = 0; nf < 4; ++nf)
        bf[nf] = *(const bf16x8*)(Bbuf + (nf * 16 + lr) * 512 +
                                  (((ko * 4 + lg) ^ (lr & 7)) << 4));
      __builtin_amdgcn_s_setprio(1);
#pragma unroll
      for (int mf = 0; mf < 4; ++mf)
#pragma unroll
        for (int nf = 0; nf < 4; ++nf)
          acc[mf][nf] = __builtin_amdgcn_mfma_f32_16x16x32_bf16(af[mf][ko], bf[nf], acc[mf][nf], 0, 0, 0);
      __builtin_amdgcn_s_setprio(0);
    }
    if (more) {
      asm volatile("s_waitcnt vmcnt(0)" ::: "memory");
      SWRITEH(nxt, 0);
      SLOADH(ct + 1, 1);
    }
#pragma unroll
    for (int ko = 4; ko < 8; ++ko) {
      bf16x8 bf[4];
#pragma unroll
      for (int nf = 0; nf < 4; ++nf)
        bf[nf] = *(const bf16x8*)(Bbuf + (nf * 16 + lr) * 512 +
                                  (((ko * 4 + lg) ^ (lr & 7)) << 4));
      __builtin_amdgcn_s_setprio(1);
#pragma unroll
      for (int mf = 0; mf < 4; ++mf)
#pragma unroll
        for (int nf = 0; nf < 4; ++nf)
          acc[mf][nf] = __builtin_amdgcn_mfma_f32_16x16x32_bf16(af[mf][ko], bf[nf], acc[mf][nf], 0, 0, 0);
      __builtin_amdgcn_s_setprio(0);
    }

    // epilogue: m = nb + BIAS - 2*dot (row norm dropped: argmin-invariant);
    // splice 14-bit col into mantissa low bits, u32 running min.
    const bool ovl = (R0 + 256 > C0) && (R0 < C0 + 64);
#pragma unroll
    for (int mf = 0; mf < 4; ++mf) {
#pragma unroll
      for (int j = 0; j < 4; ++j) {
        unsigned kmin = key[mf][j];
        const int rowg = rowbase + mf * 16 + j;
#pragma unroll
        for (int nf = 0; nf < 4; ++nf) {
          const int colg = C0 + nf * 16 + lr;
          float m = fmaf(acc[mf][nf][j], -2.0f, nb[nf]);
          unsigned q = (__builtin_bit_cast(unsigned, m) & 0xFFFFC000u) | (unsigned)colg;
          if (ovl && colg == rowg) q = 0xFFFFFFFFu;
          kmin = (q < kmin) ? q : kmin;
        }
        key[mf][j] = kmin;
      }
    }

    if (more) {
      asm volatile("s_waitcnt vmcnt(0)" ::: "memory");
      SWRITEH(nxt, 1);
      __syncthreads();
      cur = nxt;
    }
  }
#undef SLOADH
#undef SWRITEH

  // reduce across the 16 column-lanes, then global combine
#pragma unroll
  for (int mf = 0; mf < 4; ++mf) {
#pragma unroll
    for (int j = 0; j < 4; ++j) {
      unsigned k = key[mf][j];
#pragma unroll
      for (int m = 1; m < 16; m <<= 1) {
        unsigned o = __shfl_xor(k, m, 64);
        k = (o < k) ? o : k;
      }
      if (lr == 0) {
        int rowg = rowbase + mf * 16 + j;
        if (rowg < n) atomicMin(&packed[rowg], k);
      }
    }
  }
}

// ---------- 4) fused new_embed + y/idx tails ----------
__global__ __launch_bounds__(256) void k_final(
    const float* __restrict__ x, const int* __restrict__ crow,
    const int* __restrict__ brow, const unsigned* __restrict__ packed,
    const int* __restrict__ y, const int* __restrict__ idx_train,
    int N, int NT, int n, float interp, float* __restrict__ out) {
  int nb4 = (n + 3) >> 2;
  if ((int)blockIdx.x < nb4) {
    int r = blockIdx.x * 4 + (threadIdx.x >> 6);
    int lane = threadIdx.x & 63;
    if (r < n) {
      int col = (int)(packed[r] & 0x3FFFu);
      const float4* c = (const float4*)(x + ((size_t)crow[r] << 8));
      const float4* b = (const float4*)(x + ((size_t)brow[col] << 8));
      float4 cv = c[lane], bv = b[lane];
      float4 o;
      o.x = cv.x + (bv.x - cv.x) * interp;
      o.y = cv.y + (bv.y - cv.y) * interp;
      o.z = cv.z + (bv.z - cv.z) * interp;
      o.w = cv.w + (bv.w - cv.w) * interp;
      ((float4*)(out + ((size_t)N + r) * Dims))[lane] = o;
    }
    return;
  }
  long base2 = (long)(N + n) * Dims;
  long base3 = base2 + (N + n);
  int nblk = gridDim.x - nb4;
  int stride = nblk * 256;
  int start = (blockIdx.x - nb4) * 256 + threadIdx.x;
  for (int k = start; k < N + n; k += stride)
    out[base2 + k] = (k < N) ? (float)y[k] : 1.0f;
  for (int k = start; k < NT + n; k += stride)
    out[base3 + k] = (k < NT) ? (float)idx_train[k] : (float)(N + (k - NT));
}

// ---------- fallback fp32 path (ws too small / ncap too large) ----------
__global__ void k_sample(const int* __restrict__ benign, int n, unsigned span,
                         unsigned k1a, unsigned k1b, unsigned k2a, unsigned k2b,
                         unsigned mult, int* __restrict__ brow) {
  int j = blockIdx.x * blockDim.x + threadIdx.x;
  if (j >= n) return;
  unsigned a0, a1, b0, b1;
  tf2x32(k1a, k1b, 0u, (unsigned)j, &a0, &a1);
  tf2x32(k2a, k2b, 0u, (unsigned)j, &b0, &b1);
  unsigned hi = a0 ^ a1, lo = b0 ^ b1;
  unsigned r = ((hi % span) * mult + (lo % span)) % span;
  brow[j] = benign[r];
}

__global__ __launch_bounds__(64) void k_norms(
    const float* __restrict__ x, const int* __restrict__ crow,
    const int* __restrict__ brow, int n, int ncap, float* __restrict__ normc,
    float* __restrict__ normb) {
  int b = blockIdx.x;
  int lane = threadIdx.x;
  bool isC = (b < ncap);
  int j = isC ? b : (b - ncap);
  if (j >= n) {
    if (lane == 0) { if (isC) normc[j] = 0.f; else normb[j] = 3.4e38f; }
    return;
  }
  int row = isC ? crow[j] : brow[j];
  float4 v = ((const float4*)(x + ((size_t)row << 8)))[lane];
  float s = v.x * v.x + v.y * v.y + v.z * v.z + v.w * v.w;
#pragma unroll
  for (int m = 32; m >= 1; m >>= 1) s += __shfl_xor(s, m, 64);
  if (lane == 0) { if (isC) normc[j] = s; else normb[j] = s; }
}

__global__ __launch_bounds__(256) void k_dist(
    const float* __restrict__ x, const int* __restrict__ crow,
    const int* __restrict__ brow, const float* __restrict__ normc,
    const float* __restrict__ normb, int n, int* __restrict__ neigh) {
  __shared__ float cs[BM][Dims + 4];
  __shared__ float bs[BN][KC + 4];
  const int tid = threadIdx.x;
  const int tx = tid & 15, ty = tid >> 4;
  const int R0 = blockIdx.x * BM;
  const int gra = R0 + ty, grb = R0 + ty + 16;
  for (int k = tid; k < BM * (Dims / 4); k += 256) {
    int r = k >> 6, i4 = k & 63;
    int gr = R0 + r;
    float4 v = make_float4(0.f, 0.f, 0.f, 0.f);
    if (gr < n) v = *(const float4*)(x + (size_t)crow[gr] * Dims + i4 * 4);
    *(float4*)(&cs[r][i4 * 4]) = v;
  }
  float nca = 0.f, ncb = 0.f;
  if (gra < n) nca = normc[gra];
  if (grb < n) ncb = normc[grb];
  float bva = 3.4e38f, bvb = 3.4e38f;
  int bia = 0, bib = 0;
  for (int C0 = 0; C0 < n; C0 += BN) {
    float a00 = 0.f, a01 = 0.f, a10 = 0.f, a11 = 0.f;
    for (int k0 = 0; k0 < Dims; k0 += KC) {
      __syncthreads();
      for (int k = tid; k < BN * (KC / 4); k += 256) {
        int c = k >> 5, i4 = k & 31;
        int gc = C0 + c;
        float4 v = make_float4(0.f, 0.f, 0.f, 0.f);
        if (gc < n) v = *(const float4*)(x + (size_t)brow[gc] * Dims + k0 + i4 * 4);
        *(float4*)(&bs[c][i4 * 4]) = v;
      }
      __syncthreads();
#pragma unroll 8
      for (int i = 0; i < KC; i += 4) {
        float4 ca = *(const float4*)(&cs[ty][k0 + i]);
        float4 cb = *(const float4*)(&cs[ty + 16][k0 + i]);
        float4 ba = *(const float4*)(&bs[tx][i]);
        float4 bb = *(const float4*)(&bs[tx + 16][i]);
        a00 += ca.x * ba.x + ca.y * ba.y + ca.z * ba.z + ca.w * ba.w;
        a01 += ca.x * bb.x + ca.y * bb.y + ca.z * bb.z + ca.w * bb.w;
        a10 += cb.x * ba.x + cb.y * ba.y + cb.z * ba.z + cb.w * ba.w;
        a11 += cb.x * bb.x + cb.y * bb.y + cb.z * bb.z + cb.w * bb.w;
      }
    }
    int gca = C0 + tx, gcb = C0 + tx + 16;
    if (gca < n) {
      float nbv = normb[gca];
      if (gra < n && gca != gra) {
        float d2 = nca + nbv - 2.f * a00;
        if (d2 < bva) { bva = d2; bia = gca; }
      }
      if (grb < n && gca != grb) {
        float d2 = ncb + nbv - 2.f * a10;
        if (d2 < bvb) { bvb = d2; bib = gca; }
      }
    }
    if (gcb < n) {
      float nbv = normb[gcb];
      if (gra < n && gcb != gra) {
        float d2 = nca + nbv - 2.f * a01;
        if (d2 < bva) { bva = d2; bia = gcb; }
      }
      if (grb < n && gcb != grb) {
        float d2 = ncb + nbv - 2.f * a11;
        if (d2 < bvb) { bvb = d2; bib = gcb; }
      }
    }
  }
#pragma unroll
  for (int m = 1; m < 16; m <<= 1) {
    float ov = __shfl_xor(bva, m, 64);
    int oi = __shfl_xor(bia, m, 64);
    if (ov < bva || (ov == bva && oi < bia)) { bva = ov; bia = oi; }
    ov = __shfl_xor(bvb, m, 64);
    oi = __shfl_xor(bib, m, 64);
    if (ov < bvb || (ov == bvb && oi < bib)) { bvb = ov; bib = oi; }
  }
  if (tx == 0) {
    if (gra < n) neigh[gra] = bia;
    if (grb < n) neigh[grb] = bib;
  }
}

__global__ __launch_bounds__(64) void k_newembed_int(
    const float* __restrict__ x, const int* __restrict__ crow,
    const int* __restrict__ brow, const int* __restrict__ neigh,
    int N, float interp, float* __restrict__ out) {
  int r = blockIdx.x;
  int lane = threadIdx.x;
  const float4* c = (const float4*)(x + (size_t)crow[r] * Dims);
  const float4* b = (const float4*)(x + (size_t)brow[neigh[r]] * Dims);
  float4 cv = c[lane], bv = b[lane];
  float4 o;
  o.x = cv.x + (bv.x - cv.x) * interp;
  o.y = cv.y + (bv.y - cv.y) * interp;
  o.z = cv.z + (bv.z - cv.z) * interp;
  o.w = cv.w + (bv.w - cv.w) * interp;
  ((float4*)(out + ((size_t)N + r) * Dims))[lane] = o;
}

__global__ void k_tail(const int* __restrict__ y, const int* __restrict__ idx_train,
                       int N, int NT, int n, float* __restrict__ out) {
  long base2 = (long)(N + n) * Dims;
  long base3 = base2 + (N + n);
  int stride = gridDim.x * blockDim.x;
  for (int k = blockIdx.x * blockDim.x + threadIdx.x; k < N + n; k += stride)
    out[base2 + k] = (k < N) ? (float)y[k] : 1.0f;
  for (int k = blockIdx.x * blockDim.x + threadIdx.x; k < NT + n; k += stride)
    out[base3 + k] = (k < NT) ? (float)idx_train[k] : (float)(N + (k - NT));
}

extern "C" void kernel_launch(void* const* d_in, const int* in_sizes, int n_in,
                              void* d_out, int out_size, void* d_ws, size_t ws_size,
                              hipStream_t stream) {
  const float* x = (const float*)d_in[0];
  const int* y = (const int*)d_in[1];
  const int* idx_train = (const int*)d_in[2];
  float* out = (float*)d_out;
  const int N = in_sizes[1];
  const int NT = in_sizes[2];

  long nl = ((long)out_size - ((long)N * Dims + N + NT)) / (Dims + 2);
  int n = (int)nl;
  if (n < 0) n = 0;
  if (n > NT) n = NT;
  int nb = NT - n;
  int ncap = (n + 255) & ~255;
  if (ncap < 256) ncap = 256;

  size_t cap = ((size_t)NT + 255) & ~(size_t)255;
  int* chosen = (int*)d_ws;
  int* benign = chosen + cap;
  int* brow = benign + cap;
  int* neigh = brow + cap;
  float* normc = (float*)(neigh + cap);
  float* normb = normc + cap;
  unsigned* packed = (unsigned*)(normb + cap);
  unsigned short* Cb = (unsigned short*)(packed + ((ncap + 255) & ~255));
  unsigned short* Bb = Cb + (size_t)ncap * 256;
  size_t need = (char*)(Bb + (size_t)ncap * 256) - (char*)d_ws;
  bool use_mfma = (ws_size >= need) && (ncap <= 16384);

  // Host-side JAX threefry derivations from key(42)
  unsigned s0_, s1_, t0_, t1_;
  tf2x32(0u, 42u, 0u, 0u, &s0_, &s1_);
  tf2x32(0u, 42u, 0u, 1u, &t0_, &t1_);
  unsigned i0_, i1_;
  tf2x32(t0_, t1_, 0u, 0u, &i0_, &i1_);
  unsigned ub = i0_ ^ i1_;
  float interp;
  { unsigned uu = (ub >> 9) | 0x3f800000u; memcpy(&interp, &uu, 4); interp -= 1.0f; }
  unsigned k1a, k1b, k2a, k2b;
  { unsigned a, b; tf2x32(s0_, s1_, 0u, 0u, &a, &b); k1a = a; k1b = b; }
  { unsigned a, b; tf2x32(s0_, s1_, 0u, 1u, &a, &b); k2a = a; k2b = b; }
  unsigned span = (nb > 0) ? (unsigned)nb : 1u;
  unsigned m0 = 65536u % span;
  unsigned mult = (m0 * m0) % span;

  k_compact<<<1, 1024, 0, stream>>>(idx_train, y, NT, chosen, benign);
  if (n > 0 && nb > 0) {
    if (use_mfma) {
      k_prep<<<(2 * ncap) / 4, 256, 0, stream>>>(x, chosen, benign, n, ncap, span,
                                                 k1a, k1b, k2a, k2b, mult,
                                                 Cb, Bb, brow, normb, packed);
      dim3 grid(ncap / 256, NSEG);
      k_mdist<<<grid, 256, 0, stream>>>(Cb, Bb, normb, n, ncap, packed);
    } else {
      k_sample<<<(n + 255) / 256, 256, 0, stream>>>(benign, n, span, k1a, k1b, k2a, k2b, mult, brow);
      k_norms<<<2 * ncap, 64, 0, stream>>>(x, chosen, brow, n, ncap, normc, normb);
      k_dist<<<(n + BM - 1) / BM, 256, 0, stream>>>(x, chosen, brow, normc, normb, n, neigh);
    }
  }
  hipMemcpyAsync(out, x, (size_t)N * Dims * sizeof(float), hipMemcpyDeviceToDevice, stream);
  if (n > 0 && nb > 0) {
    if (use_mfma) {
      int nb4 = (n + 3) >> 2;
      k_final<<<nb4 + 128, 256, 0, stream>>>(x, chosen, brow, packed, y, idx_train,
                                             N, NT, n, interp, out);
    } else {
      k_newembed_int<<<n, 64, 0, stream>>>(x, chosen, brow, neigh, N, interp, out);
      k_tail<<<512, 256, 0, stream>>>(y, idx_train, N, NT, n, out);
    }
  } else {
    k_tail<<<512, 256, 0, stream>>>(y, idx_train, N, NT, n, out);
  }
}

// Round 6
// 417.829 us; speedup vs baseline: 1.1707x; 1.0181x over previous
//
#include <hip/hip_runtime.h>
#include <string.h>

#define Dims 256
#define BM 32
#define BN 32
#define KC 128
#define NSEG 8
#define BIAS 2048.0f

typedef short bf16x8 __attribute__((ext_vector_type(8)));
typedef float f32x4 __attribute__((ext_vector_type(4)));

// ---------- Threefry2x32 (JAX), usable host+device ----------
__host__ __device__ inline void tf2x32(unsigned k0, unsigned k1,
                                       unsigned x0, unsigned x1,
                                       unsigned* o0, unsigned* o1) {
  unsigned ks[3] = {k0, k1, k0 ^ k1 ^ 0x1BD11BDAu};
  x0 += ks[0]; x1 += ks[1];
  const unsigned rA[4] = {13u, 15u, 26u, 6u};
  const unsigned rB[4] = {17u, 29u, 16u, 24u};
#pragma unroll
  for (int g = 0; g < 5; ++g) {
    const unsigned* rr = (g & 1) ? rB : rA;
#pragma unroll
    for (int j = 0; j < 4; ++j) {
      x0 += x1;
      x1 = (x1 << rr[j]) | (x1 >> (32u - rr[j]));
      x1 ^= x0;
    }
    x0 += ks[(g + 1) % 3];
    x1 += ks[(g + 2) % 3] + (unsigned)(g + 1);
  }
  *o0 = x0; *o1 = x1;
}

__device__ inline unsigned short f2bf(float f) {
  unsigned u = __builtin_bit_cast(unsigned, f);
  unsigned r = (u + 0x7fffu + ((u >> 16) & 1u)) >> 16;
  return (unsigned short)r;
}

// ---------- 1) stable compaction ----------
__global__ __launch_bounds__(1024) void k_compact(
    const int* __restrict__ idx_train, const int* __restrict__ y, int NT,
    int* __restrict__ chosen, int* __restrict__ benign) {
  __shared__ int wsum1[16], wsum0[16], woff1[16], woff0[16];
  int t = threadIdx.x;
  int lane = t & 63, w = t >> 6;
  int ept = (NT + 1023) >> 10;
  int base = t * ept;
  int n1 = 0, n0 = 0;
  for (int k = 0; k < ept; ++k) {
    int e = base + k;
    if (e < NT) {
      int idx = idx_train[e];
      if (y[idx] == 1) n1++; else n0++;
    }
  }
  int s1 = n1, s0 = n0;
#pragma unroll
  for (int d = 1; d < 64; d <<= 1) {
    int v1 = __shfl_up(s1, d, 64);
    int v0 = __shfl_up(s0, d, 64);
    if (lane >= d) { s1 += v1; s0 += v0; }
  }
  if (lane == 63) { wsum1[w] = s1; wsum0[w] = s0; }
  __syncthreads();
  if (t == 0) {
    int a = 0, b = 0;
    for (int i = 0; i < 16; ++i) {
      woff1[i] = a; a += wsum1[i];
      woff0[i] = b; b += wsum0[i];
    }
  }
  __syncthreads();
  int p1 = woff1[w] + s1 - n1;
  int p0 = woff0[w] + s0 - n0;
  for (int k = 0; k < ept; ++k) {
    int e = base + k;
    if (e < NT) {
      int idx = idx_train[e];
      if (y[idx] == 1) chosen[p1++] = idx; else benign[p0++] = idx;
    }
  }
}

// ---------- 2) fused sample + gather + bf16 convert + norms + key init ----------
__global__ __launch_bounds__(256) void k_prep(
    const float* __restrict__ x, const int* __restrict__ chosen,
    const int* __restrict__ benign, int n, int ncap,
    unsigned span, unsigned k1a, unsigned k1b, unsigned k2a, unsigned k2b,
    unsigned mult, unsigned short* __restrict__ Cb, unsigned short* __restrict__ Bb,
    int* __restrict__ brow, float* __restrict__ normb,
    unsigned* __restrict__ packed) {
  int g = blockIdx.x * 4 + (threadIdx.x >> 6);
  int lane = threadIdx.x & 63;
  bool isC = (g < ncap);
  int j = isC ? g : (g - ncap);
  if (isC && lane == 0) packed[j] = 0xFFFFFFFFu;
  unsigned short* dst = (isC ? Cb : Bb) + ((size_t)j << 8) + lane * 4;
  if (j >= n) {
    *(ushort4*)dst = (ushort4){0, 0, 0, 0};
    if (!isC && lane == 0) normb[j] = 3.4e38f;
    return;
  }
  int row;
  if (isC) {
    row = chosen[j];
  } else {
    unsigned a0, a1, b0, b1;
    tf2x32(k1a, k1b, 0u, (unsigned)j, &a0, &a1);
    tf2x32(k2a, k2b, 0u, (unsigned)j, &b0, &b1);
    unsigned hi = a0 ^ a1, lo = b0 ^ b1;
    unsigned r = ((hi % span) * mult + (lo % span)) % span;
    row = benign[r];
    if (lane == 0) brow[j] = row;
  }
  float4 v = ((const float4*)(x + ((size_t)row << 8)))[lane];
  ushort4 o;
  o.x = f2bf(v.x); o.y = f2bf(v.y); o.z = f2bf(v.z); o.w = f2bf(v.w);
  *(ushort4*)dst = o;
  if (!isC) {
    float s = v.x * v.x + v.y * v.y + v.z * v.z + v.w * v.w;
#pragma unroll
    for (int m = 32; m >= 1; m >>= 1) s += __shfl_xor(s, m, 64);
    if (lane == 0) normb[j] = s;
  }
}

// ---------- 3) MFMA distance + argmin ----------
// 256-row blocks, A in regs. B tile (64 cols) in LDS stored in MFMA-fragment
// order: 16B unit for (col, chunk c) lives at slot
//   S  = ((col>>4)*8 + (c>>2))*64 + (c&3)*16 + (col&15)     (16B units)
//   S' = S ^ (c&7)                                          (bank spread)
// Reads are then base(nf,ko) + lane-linear with a 3-bit XOR: provably
// conflict-free for any 8/16/32-lane phasing on both write and read.
__global__ __launch_bounds__(256, 2) void k_mdist(
    const unsigned short* __restrict__ Cb, const unsigned short* __restrict__ Bb,
    const float* __restrict__ normb,
    int n, int ncap, unsigned* __restrict__ packed) {
  __shared__ __align__(16) char Bs[2][32768];
  const int tid = threadIdx.x;
  const int l = tid & 63;
  const int w = tid >> 6;
  const int lr = l & 15, lg = l >> 4;
  const int R0 = blockIdx.x * 256;
  const int ntiles = ncap >> 6;    // 64-col tiles
  const int per = (ntiles + NSEG - 1) / NSEG;
  const int t0 = blockIdx.y * per;
  int t1 = t0 + per; if (t1 > ntiles) t1 = ntiles;
  if (t0 >= t1) return;

  // staging: thread owns cols sc, sc+32; chunks sq+8i (16B units of 512B col)
  const int sc = tid >> 3;
  const int sq = tid & 7;

  uint4 sreg[4];
#define SLOADH(ct, half)                                                        \
  {                                                                             \
    const char* sb = (const char*)Bb + ((size_t)(ct) << 15) +                   \
                     (size_t)(sc + (half) * 32) * 512 + sq * 16;                \
    _Pragma("unroll") for (int i = 0; i < 4; ++i)                               \
        sreg[i] = *(const uint4*)(sb + i * 128);                                \
  }
#define SWRITEH(buf, half)                                                      \
  {                                                                             \
    char* db = Bs[buf];                                                         \
    const int colh = sc + (half) * 32;                                          \
    _Pragma("unroll") for (int i = 0; i < 4; ++i) {                             \
      const int c = sq + i * 8;                                                 \
      const int S = ((colh >> 4) * 8 + (c >> 2)) * 64 + (c & 3) * 16 +          \
                    (colh & 15);                                                \
      *(uint4*)(db + ((S ^ (c & 7)) << 4)) = sreg[i];                           \
    }                                                                           \
  }

  // prologue: stage tile t0 and pull A fragments into regs
  SLOADH(t0, 0);
  bf16x8 af[4][8];
  {
    const char* Ab = (const char*)Cb + (((size_t)(R0 + w * 64 + lr)) << 9) + lg * 16;
#pragma unroll
    for (int mf = 0; mf < 4; ++mf)
#pragma unroll
      for (int ko = 0; ko < 8; ++ko)
        af[mf][ko] = *(const bf16x8*)(Ab + mf * 8192 + ko * 64);
  }
  SWRITEH(0, 0);          // compiler inserts the vmcnt wait for sreg
  SLOADH(t0, 1);
  SWRITEH(0, 1);
  __syncthreads();

  unsigned key[4][4];
#pragma unroll
  for (int mf = 0; mf < 4; ++mf)
#pragma unroll
    for (int j = 0; j < 4; ++j) key[mf][j] = 0xFFFFFFFFu;

  const int rowbase = R0 + w * 64 + lg * 4;  // + mf*16 + j

  int cur = 0;
  for (int ct = t0; ct < t1; ++ct) {
    const int C0 = ct << 6;
    const bool more = (ct + 1 < t1);
    const int nxt = cur ^ 1;

    if (more) SLOADH(ct + 1, 0);
    float nb[4];
#pragma unroll
    for (int nf = 0; nf < 4; ++nf) nb[nf] = normb[C0 + nf * 16 + lr] + BIAS;

    f32x4 acc[4][4];
#pragma unroll
    for (int mf = 0; mf < 4; ++mf)
#pragma unroll
      for (int nf = 0; nf < 4; ++nf) acc[mf][nf] = (f32x4){0.f, 0.f, 0.f, 0.f};

    const char* Bbuf = Bs[cur];
#pragma unroll
    for (int ko = 0; ko < 4; ++ko) {
      bf16x8 bf[4];
#pragma unroll
      for (int nf = 0; nf < 4; ++nf)
        bf[nf] = *(const bf16x8*)(Bbuf +
            (((nf * 8 + ko) * 64 + lg * 16 + ((lr ^ ((ko & 1) * 4)) ^ lg)) << 4));
      __builtin_amdgcn_s_setprio(1);
#pragma unroll
      for (int mf = 0; mf < 4; ++mf)
#pragma unroll
        for (int nf = 0; nf < 4; ++nf)
          acc[mf][nf] = __builtin_amdgcn_mfma_f32_16x16x32_bf16(af[mf][ko], bf[nf], acc[mf][nf], 0, 0, 0);
      __builtin_amdgcn_s_setprio(0);
    }
    if (more) {
      SWRITEH(nxt, 0);
      SLOADH(ct + 1, 1);
    }
#pragma unroll
    for (int ko = 4; ko < 8; ++ko) {
      bf16x8 bf[4];
#pragma unroll
      for (int nf = 0; nf < 4; ++nf)
        bf[nf] = *(const bf16x8*)(Bbuf +
            (((nf * 8 + ko) * 64 + lg * 16 + ((lr ^ ((ko & 1) * 4)) ^ lg)) << 4));
      __builtin_amdgcn_s_setprio(1);
#pragma unroll
      for (int mf = 0; mf < 4; ++mf)
#pragma unroll
        for (int nf = 0; nf < 4; ++nf)
          acc[mf][nf] = __builtin_amdgcn_mfma_f32_16x16x32_bf16(af[mf][ko], bf[nf], acc[mf][nf], 0, 0, 0);
      __builtin_amdgcn_s_setprio(0);
    }

    // epilogue: m = nb + BIAS - 2*dot (row norm dropped: argmin-invariant);
    // splice 14-bit col into mantissa low bits, u32 running min.
    const bool ovl = (R0 + 256 > C0) && (R0 < C0 + 64);
#pragma unroll
    for (int mf = 0; mf < 4; ++mf) {
#pragma unroll
      for (int j = 0; j < 4; ++j) {
        unsigned kmin = key[mf][j];
        const int rowg = rowbase + mf * 16 + j;
#pragma unroll
        for (int nf = 0; nf < 4; ++nf) {
          const int colg = C0 + nf * 16 + lr;
          float m = fmaf(acc[mf][nf][j], -2.0f, nb[nf]);
          unsigned q = (__builtin_bit_cast(unsigned, m) & 0xFFFFC000u) | (unsigned)colg;
          if (ovl && colg == rowg) q = 0xFFFFFFFFu;
          kmin = (q < kmin) ? q : kmin;
        }
        key[mf][j] = kmin;
      }
    }

    if (more) {
      SWRITEH(nxt, 1);
      __syncthreads();
      cur = nxt;
    }
  }
#undef SLOADH
#undef SWRITEH

  // reduce across the 16 column-lanes, then global combine
#pragma unroll
  for (int mf = 0; mf < 4; ++mf) {
#pragma unroll
    for (int j = 0; j < 4; ++j) {
      unsigned k = key[mf][j];
#pragma unroll
      for (int m = 1; m < 16; m <<= 1) {
        unsigned o = __shfl_xor(k, m, 64);
        k = (o < k) ? o : k;
      }
      if (lr == 0) {
        int rowg = rowbase + mf * 16 + j;
        if (rowg < n) atomicMin(&packed[rowg], k);
      }
    }
  }
}

// ---------- 4) copy x -> out + y/idx tails (replaces blit memcpy) ----------
__global__ __launch_bounds__(256) void k_copy(
    const float* __restrict__ x, const int* __restrict__ y,
    const int* __restrict__ idx_train, int N, int NT, int n,
    float* __restrict__ out) {
  const size_t total4 = (size_t)N * 64;
  const size_t stride = (size_t)gridDim.x * 256;
  const float4* __restrict__ x4 = (const float4*)x;
  float4* __restrict__ o4 = (float4*)out;
  for (size_t i = (size_t)blockIdx.x * 256 + threadIdx.x; i < total4; i += stride)
    o4[i] = x4[i];
  long base2 = (long)(N + n) * Dims;
  long base3 = base2 + (N + n);
  int start = blockIdx.x * 256 + threadIdx.x;
  for (long k = start; k < N + n; k += stride)
    out[base2 + k] = (k < N) ? (float)y[k] : 1.0f;
  for (long k = start; k < NT + n; k += stride)
    out[base3 + k] = (k < NT) ? (float)idx_train[k] : (float)(N + (k - NT));
}

// ---------- 5) interpolated synthetic rows ----------
__global__ __launch_bounds__(256) void k_final(
    const float* __restrict__ x, const int* __restrict__ crow,
    const int* __restrict__ brow, const unsigned* __restrict__ packed,
    int N, int n, float interp, float* __restrict__ out) {
  int r = blockIdx.x * 4 + (threadIdx.x >> 6);
  int lane = threadIdx.x & 63;
  if (r >= n) return;
  int col = (int)(packed[r] & 0x3FFFu);
  const float4* c = (const float4*)(x + ((size_t)crow[r] << 8));
  const float4* b = (const float4*)(x + ((size_t)brow[col] << 8));
  float4 cv = c[lane], bv = b[lane];
  float4 o;
  o.x = cv.x + (bv.x - cv.x) * interp;
  o.y = cv.y + (bv.y - cv.y) * interp;
  o.z = cv.z + (bv.z - cv.z) * interp;
  o.w = cv.w + (bv.w - cv.w) * interp;
  ((float4*)(out + ((size_t)N + r) * Dims))[lane] = o;
}

// ---------- fallback fp32 path (ws too small / ncap too large) ----------
__global__ void k_sample(const int* __restrict__ benign, int n, unsigned span,
                         unsigned k1a, unsigned k1b, unsigned k2a, unsigned k2b,
                         unsigned mult, int* __restrict__ brow) {
  int j = blockIdx.x * blockDim.x + threadIdx.x;
  if (j >= n) return;
  unsigned a0, a1, b0, b1;
  tf2x32(k1a, k1b, 0u, (unsigned)j, &a0, &a1);
  tf2x32(k2a, k2b, 0u, (unsigned)j, &b0, &b1);
  unsigned hi = a0 ^ a1, lo = b0 ^ b1;
  unsigned r = ((hi % span) * mult + (lo % span)) % span;
  brow[j] = benign[r];
}

__global__ __launch_bounds__(64) void k_norms(
    const float* __restrict__ x, const int* __restrict__ crow,
    const int* __restrict__ brow, int n, int ncap, float* __restrict__ normc,
    float* __restrict__ normb) {
  int b = blockIdx.x;
  int lane = threadIdx.x;
  bool isC = (b < ncap);
  int j = isC ? b : (b - ncap);
  if (j >= n) {
    if (lane == 0) { if (isC) normc[j] = 0.f; else normb[j] = 3.4e38f; }
    return;
  }
  int row = isC ? crow[j] : brow[j];
  float4 v = ((const float4*)(x + ((size_t)row << 8)))[lane];
  float s = v.x * v.x + v.y * v.y + v.z * v.z + v.w * v.w;
#pragma unroll
  for (int m = 32; m >= 1; m >>= 1) s += __shfl_xor(s, m, 64);
  if (lane == 0) { if (isC) normc[j] = s; else normb[j] = s; }
}

__global__ __launch_bounds__(256) void k_dist(
    const float* __restrict__ x, const int* __restrict__ crow,
    const int* __restrict__ brow, const float* __restrict__ normc,
    const float* __restrict__ normb, int n, int* __restrict__ neigh) {
  __shared__ float cs[BM][Dims + 4];
  __shared__ float bs[BN][KC + 4];
  const int tid = threadIdx.x;
  const int tx = tid & 15, ty = tid >> 4;
  const int R0 = blockIdx.x * BM;
  const int gra = R0 + ty, grb = R0 + ty + 16;
  for (int k = tid; k < BM * (Dims / 4); k += 256) {
    int r = k >> 6, i4 = k & 63;
    int gr = R0 + r;
    float4 v = make_float4(0.f, 0.f, 0.f, 0.f);
    if (gr < n) v = *(const float4*)(x + (size_t)crow[gr] * Dims + i4 * 4);
    *(float4*)(&cs[r][i4 * 4]) = v;
  }
  float nca = 0.f, ncb = 0.f;
  if (gra < n) nca = normc[gra];
  if (grb < n) ncb = normc[grb];
  float bva = 3.4e38f, bvb = 3.4e38f;
  int bia = 0, bib = 0;
  for (int C0 = 0; C0 < n; C0 += BN) {
    float a00 = 0.f, a01 = 0.f, a10 = 0.f, a11 = 0.f;
    for (int k0 = 0; k0 < Dims; k0 += KC) {
      __syncthreads();
      for (int k = tid; k < BN * (KC / 4); k += 256) {
        int c = k >> 5, i4 = k & 31;
        int gc = C0 + c;
        float4 v = make_float4(0.f, 0.f, 0.f, 0.f);
        if (gc < n) v = *(const float4*)(x + (size_t)brow[gc] * Dims + k0 + i4 * 4);
        *(float4*)(&bs[c][i4 * 4]) = v;
      }
      __syncthreads();
#pragma unroll 8
      for (int i = 0; i < KC; i += 4) {
        float4 ca = *(const float4*)(&cs[ty][k0 + i]);
        float4 cb = *(const float4*)(&cs[ty + 16][k0 + i]);
        float4 ba = *(const float4*)(&bs[tx][i]);
        float4 bb = *(const float4*)(&bs[tx + 16][i]);
        a00 += ca.x * ba.x + ca.y * ba.y + ca.z * ba.z + ca.w * ba.w;
        a01 += ca.x * bb.x + ca.y * bb.y + ca.z * bb.z + ca.w * bb.w;
        a10 += cb.x * ba.x + cb.y * ba.y + cb.z * ba.z + cb.w * ba.w;
        a11 += cb.x * bb.x + cb.y * bb.y + cb.z * bb.z + cb.w * bb.w;
      }
    }
    int gca = C0 + tx, gcb = C0 + tx + 16;
    if (gca < n) {
      float nbv = normb[gca];
      if (gra < n && gca != gra) {
        float d2 = nca + nbv - 2.f * a00;
        if (d2 < bva) { bva = d2; bia = gca; }
      }
      if (grb < n && gca != grb) {
        float d2 = ncb + nbv - 2.f * a10;
        if (d2 < bvb) { bvb = d2; bib = gca; }
      }
    }
    if (gcb < n) {
      float nbv = normb[gcb];
      if (gra < n && gcb != gra) {
        float d2 = nca + nbv - 2.f * a01;
        if (d2 < bva) { bva = d2; bia = gcb; }
      }
      if (grb < n && gcb != grb) {
        float d2 = ncb + nbv - 2.f * a11;
        if (d2 < bvb) { bvb = d2; bib = gcb; }
      }
    }
  }
#pragma unroll
  for (int m = 1; m < 16; m <<= 1) {
    float ov = __shfl_xor(bva, m, 64);
    int oi = __shfl_xor(bia, m, 64);
    if (ov < bva || (ov == bva && oi < bia)) { bva = ov; bia = oi; }
    ov = __shfl_xor(bvb, m, 64);
    oi = __shfl_xor(bib, m, 64);
    if (ov < bvb || (ov == bvb && oi < bib)) { bvb = ov; bib = oi; }
  }
  if (tx == 0) {
    if (gra < n) neigh[gra] = bia;
    if (grb < n) neigh[grb] = bib;
  }
}

__global__ __launch_bounds__(64) void k_newembed_int(
    const float* __restrict__ x, const int* __restrict__ crow,
    const int* __restrict__ brow, const int* __restrict__ neigh,
    int N, float interp, float* __restrict__ out) {
  int r = blockIdx.x;
  int lane = threadIdx.x;
  const float4* c = (const float4*)(x + (size_t)crow[r] * Dims);
  const float4* b = (const float4*)(x + (size_t)brow[neigh[r]] * Dims);
  float4 cv = c[lane], bv = b[lane];
  float4 o;
  o.x = cv.x + (bv.x - cv.x) * interp;
  o.y = cv.y + (bv.y - cv.y) * interp;
  o.z = cv.z + (bv.z - cv.z) * interp;
  o.w = cv.w + (bv.w - cv.w) * interp;
  ((float4*)(out + ((size_t)N + r) * Dims))[lane] = o;
}

extern "C" void kernel_launch(void* const* d_in, const int* in_sizes, int n_in,
                              void* d_out, int out_size, void* d_ws, size_t ws_size,
                              hipStream_t stream) {
  const float* x = (const float*)d_in[0];
  const int* y = (const int*)d_in[1];
  const int* idx_train = (const int*)d_in[2];
  float* out = (float*)d_out;
  const int N = in_sizes[1];
  const int NT = in_sizes[2];

  long nl = ((long)out_size - ((long)N * Dims + N + NT)) / (Dims + 2);
  int n = (int)nl;
  if (n < 0) n = 0;
  if (n > NT) n = NT;
  int nb = NT - n;
  int ncap = (n + 255) & ~255;
  if (ncap < 256) ncap = 256;

  size_t cap = ((size_t)NT + 255) & ~(size_t)255;
  int* chosen = (int*)d_ws;
  int* benign = chosen + cap;
  int* brow = benign + cap;
  int* neigh = brow + cap;
  float* normc = (float*)(neigh + cap);
  float* normb = normc + cap;
  unsigned* packed = (unsigned*)(normb + cap);
  unsigned short* Cb = (unsigned short*)(packed + ((ncap + 255) & ~255));
  unsigned short* Bb = Cb + (size_t)ncap * 256;
  size_t need = (char*)(Bb + (size_t)ncap * 256) - (char*)d_ws;
  bool use_mfma = (ws_size >= need) && (ncap <= 16384);

  // Host-side JAX threefry derivations from key(42)
  unsigned s0_, s1_, t0_, t1_;
  tf2x32(0u, 42u, 0u, 0u, &s0_, &s1_);
  tf2x32(0u, 42u, 0u, 1u, &t0_, &t1_);
  unsigned i0_, i1_;
  tf2x32(t0_, t1_, 0u, 0u, &i0_, &i1_);
  unsigned ub = i0_ ^ i1_;
  float interp;
  { unsigned uu = (ub >> 9) | 0x3f800000u; memcpy(&interp, &uu, 4); interp -= 1.0f; }
  unsigned k1a, k1b, k2a, k2b;
  { unsigned a, b; tf2x32(s0_, s1_, 0u, 0u, &a, &b); k1a = a; k1b = b; }
  { unsigned a, b; tf2x32(s0_, s1_, 0u, 1u, &a, &b); k2a = a; k2b = b; }
  unsigned span = (nb > 0) ? (unsigned)nb : 1u;
  unsigned m0 = 65536u % span;
  unsigned mult = (m0 * m0) % span;

  k_compact<<<1, 1024, 0, stream>>>(idx_train, y, NT, chosen, benign);
  if (n > 0 && nb > 0) {
    if (use_mfma) {
      k_prep<<<(2 * ncap) / 4, 256, 0, stream>>>(x, chosen, benign, n, ncap, span,
                                                 k1a, k1b, k2a, k2b, mult,
                                                 Cb, Bb, brow, normb, packed);
      dim3 grid(ncap / 256, NSEG);
      k_mdist<<<grid, 256, 0, stream>>>(Cb, Bb, normb, n, ncap, packed);
      k_copy<<<2048, 256, 0, stream>>>(x, y, idx_train, N, NT, n, out);
      k_final<<<(n + 3) / 4, 256, 0, stream>>>(x, chosen, brow, packed, N, n, interp, out);
    } else {
      k_sample<<<(n + 255) / 256, 256, 0, stream>>>(benign, n, span, k1a, k1b, k2a, k2b, mult, brow);
      k_norms<<<2 * ncap, 64, 0, stream>>>(x, chosen, brow, n, ncap, normc, normb);
      k_dist<<<(n + BM - 1) / BM, 256, 0, stream>>>(x, chosen, brow, normc, normb, n, neigh);
      k_copy<<<2048, 256, 0, stream>>>(x, y, idx_train, N, NT, n, out);
      k_newembed_int<<<n, 64, 0, stream>>>(x, chosen, brow, neigh, N, interp, out);
    }
  } else {
    k_copy<<<2048, 256, 0, stream>>>(x, y, idx_train, N, NT, n, out);
  }
}

// Round 7
// 337.186 us; speedup vs baseline: 1.4507x; 1.2392x over previous
//
#include <hip/hip_runtime.h>
#include <string.h>

#define Dims 256
#define BM 32
#define BN 32
#define KC 128
#define BIAS 2048.0f

typedef float f32x4 __attribute__((ext_vector_type(4)));

// ---------- Threefry2x32 (JAX), usable host+device ----------
__host__ __device__ inline void tf2x32(unsigned k0, unsigned k1,
                                       unsigned x0, unsigned x1,
                                       unsigned* o0, unsigned* o1) {
  unsigned ks[3] = {k0, k1, k0 ^ k1 ^ 0x1BD11BDAu};
  x0 += ks[0]; x1 += ks[1];
  const unsigned rA[4] = {13u, 15u, 26u, 6u};
  const unsigned rB[4] = {17u, 29u, 16u, 24u};
#pragma unroll
  for (int g = 0; g < 5; ++g) {
    const unsigned* rr = (g & 1) ? rB : rA;
#pragma unroll
    for (int j = 0; j < 4; ++j) {
      x0 += x1;
      x1 = (x1 << rr[j]) | (x1 >> (32u - rr[j]));
      x1 ^= x0;
    }
    x0 += ks[(g + 1) % 3];
    x1 += ks[(g + 2) % 3] + (unsigned)(g + 1);
  }
  *o0 = x0; *o1 = x1;
}

// f32 -> fp8 e4m3fn (RNE, saturate to 448, flush |x|<2^-6 to 0)
__device__ inline unsigned f2e4m3(float f) {
  unsigned u = __builtin_bit_cast(unsigned, f);
  unsigned s = (u >> 24) & 0x80u;
  int e = (int)((u >> 23) & 0xFFu) - 127;
  unsigned m = u & 0x7FFFFFu;
  if (e < -6) return s;
  unsigned mr = m + 0x7FFFFu + ((m >> 20) & 1u);
  unsigned mm;
  if (mr & 0x800000u) { mm = 0u; e += 1; } else mm = mr >> 20;
  if (e > 8) return s | 0x7Eu;
  return s | ((unsigned)(e + 7) << 3) | mm;
}

// ---------- 1) stable compaction ----------
__global__ __launch_bounds__(1024) void k_compact(
    const int* __restrict__ idx_train, const int* __restrict__ y, int NT,
    int* __restrict__ chosen, int* __restrict__ benign) {
  __shared__ int wsum1[16], wsum0[16], woff1[16], woff0[16];
  int t = threadIdx.x;
  int lane = t & 63, w = t >> 6;
  int ept = (NT + 1023) >> 10;
  int base = t * ept;
  int n1 = 0, n0 = 0;
  for (int k = 0; k < ept; ++k) {
    int e = base + k;
    if (e < NT) {
      int idx = idx_train[e];
      if (y[idx] == 1) n1++; else n0++;
    }
  }
  int s1 = n1, s0 = n0;
#pragma unroll
  for (int d = 1; d < 64; d <<= 1) {
    int v1 = __shfl_up(s1, d, 64);
    int v0 = __shfl_up(s0, d, 64);
    if (lane >= d) { s1 += v1; s0 += v0; }
  }
  if (lane == 63) { wsum1[w] = s1; wsum0[w] = s0; }
  __syncthreads();
  if (t == 0) {
    int a = 0, b = 0;
    for (int i = 0; i < 16; ++i) {
      woff1[i] = a; a += wsum1[i];
      woff0[i] = b; b += wsum0[i];
    }
  }
  __syncthreads();
  int p1 = woff1[w] + s1 - n1;
  int p0 = woff0[w] + s0 - n0;
  for (int k = 0; k < ept; ++k) {
    int e = base + k;
    if (e < NT) {
      int idx = idx_train[e];
      if (y[idx] == 1) chosen[p1++] = idx; else benign[p0++] = idx;
    }
  }
}

// ---------- 2) fused sample + gather + fp8 convert + norms + key init ----------
__global__ __launch_bounds__(256) void k_prep(
    const float* __restrict__ x, const int* __restrict__ chosen,
    const int* __restrict__ benign, int n, int ncap,
    unsigned span, unsigned k1a, unsigned k1b, unsigned k2a, unsigned k2b,
    unsigned mult, unsigned char* __restrict__ Cb, unsigned char* __restrict__ Bb,
    int* __restrict__ brow, float* __restrict__ normb,
    unsigned* __restrict__ packed) {
  int g = blockIdx.x * 4 + (threadIdx.x >> 6);
  int lane = threadIdx.x & 63;
  bool isC = (g < ncap);
  int j = isC ? g : (g - ncap);
  if (isC && lane == 0) packed[j] = 0xFFFFFFFFu;
  unsigned char* dst = (isC ? Cb : Bb) + ((size_t)j << 8) + lane * 4;
  if (j >= n) {
    *(unsigned*)dst = 0u;
    if (!isC && lane == 0) normb[j] = 3.4e38f;
    return;
  }
  int row;
  if (isC) {
    row = chosen[j];
  } else {
    unsigned a0, a1, b0, b1;
    tf2x32(k1a, k1b, 0u, (unsigned)j, &a0, &a1);
    tf2x32(k2a, k2b, 0u, (unsigned)j, &b0, &b1);
    unsigned hi = a0 ^ a1, lo = b0 ^ b1;
    unsigned r = ((hi % span) * mult + (lo % span)) % span;
    row = benign[r];
    if (lane == 0) brow[j] = row;
  }
  float4 v = ((const float4*)(x + ((size_t)row << 8)))[lane];
  unsigned p = f2e4m3(v.x) | (f2e4m3(v.y) << 8) | (f2e4m3(v.z) << 16) |
               (f2e4m3(v.w) << 24);
  *(unsigned*)dst = p;
  if (!isC) {
    float s = v.x * v.x + v.y * v.y + v.z * v.z + v.w * v.w;
#pragma unroll
    for (int m = 32; m >= 1; m >>= 1) s += __shfl_xor(s, m, 64);
    if (lane == 0) normb[j] = s;
  }
}

// ---------- 3) fused: fp8 MFMA distance+argmin (blocks 0..nrb*8-1) + x-copy/tails ----------
// LDS layout (8B units): unit for (col,c) at S^f(c), S = ((col>>4)*8+(c>>2))*64
// + (c&3)*16 + (col&15), f(c) = (c&7)|((c&1)<<3). Read for (nf,ko) is
// lane-linear; both read and write verified 4 lanes per bank-class (minimum).
__global__ __launch_bounds__(256, 2) void k_main(
    const unsigned char* __restrict__ Cb, const unsigned char* __restrict__ Bb,
    const float* __restrict__ normb, const float* __restrict__ x,
    const int* __restrict__ y, const int* __restrict__ idx_train,
    int n, int ncap, int nrb, int N, int NT,
    unsigned* __restrict__ packed, float* __restrict__ out) {
  const int nbmd = nrb * 8;
  if ((int)blockIdx.x >= nbmd) {
    // ---- copy part: x -> out, plus y/idx tails ----
    const int cid = blockIdx.x - nbmd;
    const int ncb = gridDim.x - nbmd;
    const size_t stride = (size_t)ncb * 256;
    const size_t total4 = (size_t)N * 64;
    const float4* __restrict__ x4 = (const float4*)x;
    float4* __restrict__ o4 = (float4*)out;
    for (size_t i = (size_t)cid * 256 + threadIdx.x; i < total4; i += stride)
      o4[i] = x4[i];
    long base2 = (long)(N + n) * Dims;
    long base3 = base2 + (N + n);
    long start = (long)cid * 256 + threadIdx.x;
    for (long k = start; k < N + n; k += stride)
      out[base2 + k] = (k < N) ? (float)y[k] : 1.0f;
    for (long k = start; k < NT + n; k += stride)
      out[base3 + k] = (k < NT) ? (float)idx_train[k] : (float)(N + (k - NT));
    return;
  }
  __shared__ __align__(16) char Bs[2][16384];
  const int tid = threadIdx.x;
  const int l = tid & 63;
  const int w = tid >> 6;
  const int lr = l & 15, lg = l >> 4;
  const int seg = blockIdx.x & 7;          // one B-segment per XCD (L2 locality)
  const int R0 = (blockIdx.x >> 3) * 256;
  const int ntiles = ncap >> 6;
  const int per = (ntiles + 7) >> 3;
  const int t0 = seg * per;
  int t1 = t0 + per; if (t1 > ntiles) t1 = ntiles;
  if (t0 >= t1) return;

  // staging: thread owns col sc(+32), 8B chunks sq+8i
  const int sc = tid >> 3;
  const int sq = tid & 7;
  const int sqm = sq | ((sq & 1) << 3);    // f(c) for c=sq+8i (i-independent)
  const int lgm = lg | ((lg & 1) << 3);    // f(c) lane part for reads

  long sreg[4];
#define SLOADH(ct, half)                                                        \
  {                                                                             \
    const char* sb = (const char*)Bb + ((size_t)(ct) << 14) +                   \
                     (size_t)(sc + (half) * 32) * 256 + sq * 8;                 \
    _Pragma("unroll") for (int i = 0; i < 4; ++i)                               \
        sreg[i] = *(const long*)(sb + i * 64);                                  \
  }
#define SWRITEH(buf, half)                                                      \
  {                                                                             \
    char* db = Bs[buf];                                                         \
    const int colh = sc + (half) * 32;                                          \
    _Pragma("unroll") for (int i = 0; i < 4; ++i) {                             \
      const int c = sq + 8 * i;                                                 \
      const int S = ((colh >> 4) * 8 + (c >> 2)) * 64 + (c & 3) * 16 +          \
                    (colh & 15);                                                \
      *(long*)(db + ((S ^ sqm) << 3)) = sreg[i];                                \
    }                                                                           \
  }

  // prologue: stage tile t0; pull A fragments (fp8, 8B each) into regs
  SLOADH(t0, 0);
  long af[4][8];
  {
    const char* Ab = (const char*)Cb + (size_t)(R0 + w * 64 + lr) * 256 + lg * 8;
#pragma unroll
    for (int mf = 0; mf < 4; ++mf)
#pragma unroll
      for (int ko = 0; ko < 8; ++ko)
        af[mf][ko] = *(const long*)(Ab + mf * 4096 + ko * 32);
  }
  SWRITEH(0, 0);
  SLOADH(t0, 1);
  SWRITEH(0, 1);
  __syncthreads();

  unsigned key[4][4];
#pragma unroll
  for (int mf = 0; mf < 4; ++mf)
#pragma unroll
    for (int j = 0; j < 4; ++j) key[mf][j] = 0xFFFFFFFFu;

  const int rowbase = R0 + w * 64 + lg * 4;  // + mf*16 + j

  int cur = 0;
  for (int ct = t0; ct < t1; ++ct) {
    const int C0 = ct << 6;
    const bool more = (ct + 1 < t1);
    const int nxt = cur ^ 1;

    if (more) SLOADH(ct + 1, 0);
    float nb[4];
#pragma unroll
    for (int nf = 0; nf < 4; ++nf) nb[nf] = normb[C0 + nf * 16 + lr] + BIAS;

    f32x4 acc[4][4];
#pragma unroll
    for (int mf = 0; mf < 4; ++mf)
#pragma unroll
      for (int nf = 0; nf < 4; ++nf) acc[mf][nf] = (f32x4){0.f, 0.f, 0.f, 0.f};

    const char* Bbuf = Bs[cur];
#pragma unroll
    for (int ko = 0; ko < 4; ++ko) {
      long bf[4];
#pragma unroll
      for (int nf = 0; nf < 4; ++nf)
        bf[nf] = *(const long*)(Bbuf +
            (((nf * 8 + ko) * 64 + lg * 16 + (lr ^ lgm ^ ((ko & 1) << 2))) << 3));
      __builtin_amdgcn_s_setprio(1);
#pragma unroll
      for (int mf = 0; mf < 4; ++mf)
#pragma unroll
        for (int nf = 0; nf < 4; ++nf)
          acc[mf][nf] = __builtin_amdgcn_mfma_f32_16x16x32_fp8_fp8(
              af[mf][ko], bf[nf], acc[mf][nf], 0, 0, 0);
      __builtin_amdgcn_s_setprio(0);
    }
    if (more) {
      SWRITEH(nxt, 0);
      SLOADH(ct + 1, 1);
    }
#pragma unroll
    for (int ko = 4; ko < 8; ++ko) {
      long bf[4];
#pragma unroll
      for (int nf = 0; nf < 4; ++nf)
        bf[nf] = *(const long*)(Bbuf +
            (((nf * 8 + ko) * 64 + lg * 16 + (lr ^ lgm ^ ((ko & 1) << 2))) << 3));
      __builtin_amdgcn_s_setprio(1);
#pragma unroll
      for (int mf = 0; mf < 4; ++mf)
#pragma unroll
        for (int nf = 0; nf < 4; ++nf)
          acc[mf][nf] = __builtin_amdgcn_mfma_f32_16x16x32_fp8_fp8(
              af[mf][ko], bf[nf], acc[mf][nf], 0, 0, 0);
      __builtin_amdgcn_s_setprio(0);
    }

    // epilogue: m = nb + BIAS - 2*dot (row norm dropped: argmin-invariant);
    // splice 14-bit col into mantissa low bits, u32 running min.
    const bool ovl = (R0 + 256 > C0) && (R0 < C0 + 64);
#pragma unroll
    for (int mf = 0; mf < 4; ++mf) {
#pragma unroll
      for (int j = 0; j < 4; ++j) {
        unsigned kmin = key[mf][j];
        const int rowg = rowbase + mf * 16 + j;
#pragma unroll
        for (int nf = 0; nf < 4; ++nf) {
          const int colg = C0 + nf * 16 + lr;
          float m = fmaf(acc[mf][nf][j], -2.0f, nb[nf]);
          unsigned q = (__builtin_bit_cast(unsigned, m) & 0xFFFFC000u) | (unsigned)colg;
          if (ovl && colg == rowg) q = 0xFFFFFFFFu;
          kmin = (q < kmin) ? q : kmin;
        }
        key[mf][j] = kmin;
      }
    }

    if (more) {
      SWRITEH(nxt, 1);
      __syncthreads();
      cur = nxt;
    }
  }
#undef SLOADH
#undef SWRITEH

#pragma unroll
  for (int mf = 0; mf < 4; ++mf) {
#pragma unroll
    for (int j = 0; j < 4; ++j) {
      unsigned k = key[mf][j];
#pragma unroll
      for (int m = 1; m < 16; m <<= 1) {
        unsigned o = __shfl_xor(k, m, 64);
        k = (o < k) ? o : k;
      }
      if (lr == 0) {
        int rowg = rowbase + mf * 16 + j;
        if (rowg < n) atomicMin(&packed[rowg], k);
      }
    }
  }
}

// ---------- 4) interpolated synthetic rows ----------
__global__ __launch_bounds__(256) void k_final(
    const float* __restrict__ x, const int* __restrict__ crow,
    const int* __restrict__ brow, const unsigned* __restrict__ packed,
    int N, int n, float interp, float* __restrict__ out) {
  int r = blockIdx.x * 4 + (threadIdx.x >> 6);
  int lane = threadIdx.x & 63;
  if (r >= n) return;
  int col = (int)(packed[r] & 0x3FFFu);
  const float4* c = (const float4*)(x + ((size_t)crow[r] << 8));
  const float4* b = (const float4*)(x + ((size_t)brow[col] << 8));
  float4 cv = c[lane], bv = b[lane];
  float4 o;
  o.x = cv.x + (bv.x - cv.x) * interp;
  o.y = cv.y + (bv.y - cv.y) * interp;
  o.z = cv.z + (bv.z - cv.z) * interp;
  o.w = cv.w + (bv.w - cv.w) * interp;
  ((float4*)(out + ((size_t)N + r) * Dims))[lane] = o;
}

// ---------- standalone copy (fallback path) ----------
__global__ __launch_bounds__(256) void k_copy(
    const float* __restrict__ x, const int* __restrict__ y,
    const int* __restrict__ idx_train, int N, int NT, int n,
    float* __restrict__ out) {
  const size_t total4 = (size_t)N * 64;
  const size_t stride = (size_t)gridDim.x * 256;
  const float4* __restrict__ x4 = (const float4*)x;
  float4* __restrict__ o4 = (float4*)out;
  for (size_t i = (size_t)blockIdx.x * 256 + threadIdx.x; i < total4; i += stride)
    o4[i] = x4[i];
  long base2 = (long)(N + n) * Dims;
  long base3 = base2 + (N + n);
  long start = (long)blockIdx.x * 256 + threadIdx.x;
  for (long k = start; k < N + n; k += stride)
    out[base2 + k] = (k < N) ? (float)y[k] : 1.0f;
  for (long k = start; k < NT + n; k += stride)
    out[base3 + k] = (k < NT) ? (float)idx_train[k] : (float)(N + (k - NT));
}

// ---------- fallback fp32 path ----------
__global__ void k_sample(const int* __restrict__ benign, int n, unsigned span,
                         unsigned k1a, unsigned k1b, unsigned k2a, unsigned k2b,
                         unsigned mult, int* __restrict__ brow) {
  int j = blockIdx.x * blockDim.x + threadIdx.x;
  if (j >= n) return;
  unsigned a0, a1, b0, b1;
  tf2x32(k1a, k1b, 0u, (unsigned)j, &a0, &a1);
  tf2x32(k2a, k2b, 0u, (unsigned)j, &b0, &b1);
  unsigned hi = a0 ^ a1, lo = b0 ^ b1;
  unsigned r = ((hi % span) * mult + (lo % span)) % span;
  brow[j] = benign[r];
}

__global__ __launch_bounds__(64) void k_norms(
    const float* __restrict__ x, const int* __restrict__ crow,
    const int* __restrict__ brow, int n, int ncap, float* __restrict__ normc,
    float* __restrict__ normb) {
  int b = blockIdx.x;
  int lane = threadIdx.x;
  bool isC = (b < ncap);
  int j = isC ? b : (b - ncap);
  if (j >= n) {
    if (lane == 0) { if (isC) normc[j] = 0.f; else normb[j] = 3.4e38f; }
    return;
  }
  int row = isC ? crow[j] : brow[j];
  float4 v = ((const float4*)(x + ((size_t)row << 8)))[lane];
  float s = v.x * v.x + v.y * v.y + v.z * v.z + v.w * v.w;
#pragma unroll
  for (int m = 32; m >= 1; m >>= 1) s += __shfl_xor(s, m, 64);
  if (lane == 0) { if (isC) normc[j] = s; else normb[j] = s; }
}

__global__ __launch_bounds__(256) void k_dist(
    const float* __restrict__ x, const int* __restrict__ crow,
    const int* __restrict__ brow, const float* __restrict__ normc,
    const float* __restrict__ normb, int n, int* __restrict__ neigh) {
  __shared__ float cs[BM][Dims + 4];
  __shared__ float bs[BN][KC + 4];
  const int tid = threadIdx.x;
  const int tx = tid & 15, ty = tid >> 4;
  const int R0 = blockIdx.x * BM;
  const int gra = R0 + ty, grb = R0 + ty + 16;
  for (int k = tid; k < BM * (Dims / 4); k += 256) {
    int r = k >> 6, i4 = k & 63;
    int gr = R0 + r;
    float4 v = make_float4(0.f, 0.f, 0.f, 0.f);
    if (gr < n) v = *(const float4*)(x + (size_t)crow[gr] * Dims + i4 * 4);
    *(float4*)(&cs[r][i4 * 4]) = v;
  }
  float nca = 0.f, ncb = 0.f;
  if (gra < n) nca = normc[gra];
  if (grb < n) ncb = normc[grb];
  float bva = 3.4e38f, bvb = 3.4e38f;
  int bia = 0, bib = 0;
  for (int C0 = 0; C0 < n; C0 += BN) {
    float a00 = 0.f, a01 = 0.f, a10 = 0.f, a11 = 0.f;
    for (int k0 = 0; k0 < Dims; k0 += KC) {
      __syncthreads();
      for (int k = tid; k < BN * (KC / 4); k += 256) {
        int c = k >> 5, i4 = k & 31;
        int gc = C0 + c;
        float4 v = make_float4(0.f, 0.f, 0.f, 0.f);
        if (gc < n) v = *(const float4*)(x + (size_t)brow[gc] * Dims + k0 + i4 * 4);
        *(float4*)(&bs[c][i4 * 4]) = v;
      }
      __syncthreads();
#pragma unroll 8
      for (int i = 0; i < KC; i += 4) {
        float4 ca = *(const float4*)(&cs[ty][k0 + i]);
        float4 cb = *(const float4*)(&cs[ty + 16][k0 + i]);
        float4 ba = *(const float4*)(&bs[tx][i]);
        float4 bb = *(const float4*)(&bs[tx + 16][i]);
        a00 += ca.x * ba.x + ca.y * ba.y + ca.z * ba.z + ca.w * ba.w;
        a01 += ca.x * bb.x + ca.y * bb.y + ca.z * bb.z + ca.w * bb.w;
        a10 += cb.x * ba.x + cb.y * ba.y + cb.z * ba.z + cb.w * ba.w;
        a11 += cb.x * bb.x + cb.y * bb.y + cb.z * bb.z + cb.w * bb.w;
      }
    }
    int gca = C0 + tx, gcb = C0 + tx + 16;
    if (gca < n) {
      float nbv = normb[gca];
      if (gra < n && gca != gra) {
        float d2 = nca + nbv - 2.f * a00;
        if (d2 < bva) { bva = d2; bia = gca; }
      }
      if (grb < n && gca != grb) {
        float d2 = ncb + nbv - 2.f * a10;
        if (d2 < bvb) { bvb = d2; bib = gca; }
      }
    }
    if (gcb < n) {
      float nbv = normb[gcb];
      if (gra < n && gcb != gra) {
        float d2 = nca + nbv - 2.f * a01;
        if (d2 < bva) { bva = d2; bia = gcb; }
      }
      if (grb < n && gcb != grb) {
        float d2 = ncb + nbv - 2.f * a11;
        if (d2 < bvb) { bvb = d2; bib = gcb; }
      }
    }
  }
#pragma unroll
  for (int m = 1; m < 16; m <<= 1) {
    float ov = __shfl_xor(bva, m, 64);
    int oi = __shfl_xor(bia, m, 64);
    if (ov < bva || (ov == bva && oi < bia)) { bva = ov; bia = oi; }
    ov = __shfl_xor(bvb, m, 64);
    oi = __shfl_xor(bib, m, 64);
    if (ov < bvb || (ov == bvb && oi < bib)) { bvb = ov; bib = oi; }
  }
  if (tx == 0) {
    if (gra < n) neigh[gra] = bia;
    if (grb < n) neigh[grb] = bib;
  }
}

__global__ __launch_bounds__(64) void k_newembed_int(
    const float* __restrict__ x, const int* __restrict__ crow,
    const int* __restrict__ brow, const int* __restrict__ neigh,
    int N, float interp, float* __restrict__ out) {
  int r = blockIdx.x;
  int lane = threadIdx.x;
  const float4* c = (const float4*)(x + (size_t)crow[r] * Dims);
  const float4* b = (const float4*)(x + (size_t)brow[neigh[r]] * Dims);
  float4 cv = c[lane], bv = b[lane];
  float4 o;
  o.x = cv.x + (bv.x - cv.x) * interp;
  o.y = cv.y + (bv.y - cv.y) * interp;
  o.z = cv.z + (bv.z - cv.z) * interp;
  o.w = cv.w + (bv.w - cv.w) * interp;
  ((float4*)(out + ((size_t)N + r) * Dims))[lane] = o;
}

extern "C" void kernel_launch(void* const* d_in, const int* in_sizes, int n_in,
                              void* d_out, int out_size, void* d_ws, size_t ws_size,
                              hipStream_t stream) {
  const float* x = (const float*)d_in[0];
  const int* y = (const int*)d_in[1];
  const int* idx_train = (const int*)d_in[2];
  float* out = (float*)d_out;
  const int N = in_sizes[1];
  const int NT = in_sizes[2];

  long nl = ((long)out_size - ((long)N * Dims + N + NT)) / (Dims + 2);
  int n = (int)nl;
  if (n < 0) n = 0;
  if (n > NT) n = NT;
  int nb = NT - n;
  int ncap = (n + 255) & ~255;
  if (ncap < 256) ncap = 256;

  size_t cap = ((size_t)NT + 255) & ~(size_t)255;
  int* chosen = (int*)d_ws;
  int* benign = chosen + cap;
  int* brow = benign + cap;
  int* neigh = brow + cap;
  float* normc = (float*)(neigh + cap);
  float* normb = normc + cap;
  unsigned* packed = (unsigned*)(normb + cap);
  unsigned char* Cb = (unsigned char*)(packed + ((ncap + 255) & ~255));
  unsigned char* Bb = Cb + (size_t)ncap * 256;
  size_t need = (char*)(Bb + (size_t)ncap * 256) - (char*)d_ws;
  bool use_mfma = (ws_size >= need) && (ncap <= 16384);

  // Host-side JAX threefry derivations from key(42)
  unsigned s0_, s1_, t0_, t1_;
  tf2x32(0u, 42u, 0u, 0u, &s0_, &s1_);
  tf2x32(0u, 42u, 0u, 1u, &t0_, &t1_);
  unsigned i0_, i1_;
  tf2x32(t0_, t1_, 0u, 0u, &i0_, &i1_);
  unsigned ub = i0_ ^ i1_;
  float interp;
  { unsigned uu = (ub >> 9) | 0x3f800000u; memcpy(&interp, &uu, 4); interp -= 1.0f; }
  unsigned k1a, k1b, k2a, k2b;
  { unsigned a, b; tf2x32(s0_, s1_, 0u, 0u, &a, &b); k1a = a; k1b = b; }
  { unsigned a, b; tf2x32(s0_, s1_, 0u, 1u, &a, &b); k2a = a; k2b = b; }
  unsigned span = (nb > 0) ? (unsigned)nb : 1u;
  unsigned m0 = 65536u % span;
  unsigned mult = (m0 * m0) % span;

  k_compact<<<1, 1024, 0, stream>>>(idx_train, y, NT, chosen, benign);
  if (n > 0 && nb > 0) {
    if (use_mfma) {
      k_prep<<<(2 * ncap) / 4, 256, 0, stream>>>(x, chosen, benign, n, ncap, span,
                                                 k1a, k1b, k2a, k2b, mult,
                                                 Cb, Bb, brow, normb, packed);
      int nrb = ncap / 256;
      int nbmd = nrb * 8;
      int nbcp = 1536;
      k_main<<<nbmd + nbcp, 256, 0, stream>>>(Cb, Bb, normb, x, y, idx_train,
                                              n, ncap, nrb, N, NT, packed, out);
      k_final<<<(n + 3) / 4, 256, 0, stream>>>(x, chosen, brow, packed, N, n, interp, out);
    } else {
      k_sample<<<(n + 255) / 256, 256, 0, stream>>>(benign, n, span, k1a, k1b, k2a, k2b, mult, brow);
      k_norms<<<2 * ncap, 64, 0, stream>>>(x, chosen, brow, n, ncap, normc, normb);
      k_dist<<<(n + BM - 1) / BM, 256, 0, stream>>>(x, chosen, brow, normc, normb, n, neigh);
      k_copy<<<2048, 256, 0, stream>>>(x, y, idx_train, N, NT, n, out);
      k_newembed_int<<<n, 64, 0, stream>>>(x, chosen, brow, neigh, N, interp, out);
    }
  } else {
    k_copy<<<2048, 256, 0, stream>>>(x, y, idx_train, N, NT, n, out);
  }
}